// Round 1
// baseline (5229.886 us; speedup 1.0000x reference)
//
#include <hip/hip_runtime.h>
#include <hip/hip_bf16.h>

// Shapes (fixed by the reference): B=8, N=M=128, D=1024, H=512
static constexpr int Bc = 8, Nc = 128, Dc = 1024, Hc = 512;
static constexpr int BM = Bc * Nc;  // 1024

__device__ __forceinline__ float fast_tanh(float x) {
  x = fminf(fmaxf(x, -15.f), 15.f);
  float e = __expf(2.f * x);
  return (e - 1.f) / (e + 1.f);
}

// sum over 256-thread block; result broadcast to all threads
__device__ __forceinline__ float block_sum256(float v, float* buf4) {
  #pragma unroll
  for (int o = 32; o; o >>= 1) v += __shfl_down(v, o, 64);
  const int w = threadIdx.x >> 6, lane = threadIdx.x & 63;
  if (lane == 0) buf4[w] = v;
  __syncthreads();
  return buf4[0] + buf4[1] + buf4[2] + buf4[3];
}

// C[r,j] = sum_k A[r,k]*W[k,j]; R multiple of 64 (grid.y), J multiple of 64, K multiple of 16
__global__ __launch_bounds__(256) void gemm_rm(const float* __restrict__ A,
                                               const float* __restrict__ W,
                                               float* __restrict__ C,
                                               int K, int J) {
  __shared__ __align__(16) float As[16][64];
  __shared__ __align__(16) float Ws[16][64];
  const int tid = threadIdx.x;
  const int tx = tid & 15, ty = tid >> 4;
  const int rowBase = blockIdx.y * 64;
  const int colBase = blockIdx.x * 64;
  float acc[4][4] = {};
  for (int k0 = 0; k0 < K; k0 += 16) {
    #pragma unroll
    for (int i = 0; i < 4; i++) {
      int idx = tid + i * 256;
      int m = idx >> 4, k = idx & 15;
      As[k][m] = A[(size_t)(rowBase + m) * K + k0 + k];
    }
    #pragma unroll
    for (int i = 0; i < 4; i++) {
      int idx = tid + i * 256;
      int k = idx >> 6, j = idx & 63;
      Ws[k][j] = W[(size_t)(k0 + k) * J + colBase + j];
    }
    __syncthreads();
    #pragma unroll
    for (int k = 0; k < 16; k++) {
      float4 av = *reinterpret_cast<const float4*>(&As[k][ty * 4]);
      float4 wv = *reinterpret_cast<const float4*>(&Ws[k][tx * 4]);
      float a_[4] = {av.x, av.y, av.z, av.w};
      float w_[4] = {wv.x, wv.y, wv.z, wv.w};
      #pragma unroll
      for (int i = 0; i < 4; i++)
        #pragma unroll
        for (int j = 0; j < 4; j++)
          acc[i][j] = fmaf(a_[i], w_[j], acc[i][j]);
    }
    __syncthreads();
  }
  #pragma unroll
  for (int i = 0; i < 4; i++)
    #pragma unroll
    for (int j = 0; j < 4; j++)
      C[(size_t)(rowBase + ty * 4 + i) * J + colBase + tx * 4 + j] = acc[i][j];
}

// s[b,m,n] += sum_h v[h]*tanh( sum_d X[b,n,d]*Y[b,m,d]*Wd[d,h] ), h-tile per block.x
// grid: (Hc/64, Nc/64, BM); S must be pre-zeroed (atomic accumulate across h-tiles)
__global__ __launch_bounds__(256) void dot_scores(const float* __restrict__ X,
                                                  const float* __restrict__ Y,
                                                  const float* __restrict__ Wd,
                                                  const float* __restrict__ v,
                                                  float* __restrict__ S) {
  const int bm = blockIdx.z;
  const int b = bm >> 7;
  const int nBase = blockIdx.y * 64;
  const int hBase = blockIdx.x * 64;
  const int tid = threadIdx.x;
  const int tx = tid & 15, ty = tid >> 4;

  __shared__ __align__(16) float yrow[Dc];
  __shared__ __align__(16) float As[16][64];
  __shared__ __align__(16) float Ws[16][64];
  __shared__ float red[64][17];

  const float* Yrow = Y + (size_t)bm * Dc;
  for (int i = tid; i < Dc; i += 256) yrow[i] = Yrow[i];
  __syncthreads();

  const float* Xb = X + (size_t)b * Nc * Dc;
  float acc[4][4] = {};
  for (int k0 = 0; k0 < Dc; k0 += 16) {
    #pragma unroll
    for (int i = 0; i < 4; i++) {
      int idx = tid + i * 256;
      int m = idx >> 4, k = idx & 15;
      As[k][m] = Xb[(size_t)(nBase + m) * Dc + k0 + k] * yrow[k0 + k];
    }
    #pragma unroll
    for (int i = 0; i < 4; i++) {
      int idx = tid + i * 256;
      int k = idx >> 6, j = idx & 63;
      Ws[k][j] = Wd[(size_t)(k0 + k) * Hc + hBase + j];
    }
    __syncthreads();
    #pragma unroll
    for (int k = 0; k < 16; k++) {
      float4 av = *reinterpret_cast<const float4*>(&As[k][ty * 4]);
      float4 wv = *reinterpret_cast<const float4*>(&Ws[k][tx * 4]);
      float a_[4] = {av.x, av.y, av.z, av.w};
      float w_[4] = {wv.x, wv.y, wv.z, wv.w};
      #pragma unroll
      for (int i = 0; i < 4; i++)
        #pragma unroll
        for (int j = 0; j < 4; j++)
          acc[i][j] = fmaf(a_[i], w_[j], acc[i][j]);
    }
    __syncthreads();
  }
  float4 vv = *reinterpret_cast<const float4*>(&v[hBase + tx * 4]);
  float v_[4] = {vv.x, vv.y, vv.z, vv.w};
  #pragma unroll
  for (int i = 0; i < 4; i++) {
    float p = 0.f;
    #pragma unroll
    for (int j = 0; j < 4; j++) p = fmaf(fast_tanh(acc[i][j]), v_[j], p);
    red[ty * 4 + i][tx] = p;
  }
  __syncthreads();
  if (tid < 64) {
    float s = 0.f;
    #pragma unroll
    for (int t = 0; t < 16; t++) s += red[tid][t];
    atomicAdd(&S[(size_t)bm * Nc + nBase + tid], s);
  }
}

// s[b,m,n] = sum_h v[h]*tanh(An[b,n,h] + sign*Bm[b,m,h]); grid (Nc, BM)
__global__ __launch_bounds__(256) void addtanh_scores(const float* __restrict__ An,
                                                      const float* __restrict__ Bm,
                                                      const float* __restrict__ v,
                                                      float sign,
                                                      float* __restrict__ S) {
  const int n = blockIdx.x;
  const int bm = blockIdx.y;
  const int b = bm >> 7;
  const float* arow = An + (size_t)(b * Nc + n) * Hc;
  const float* brow = Bm + (size_t)bm * Hc;
  const int tid = threadIdx.x;
  float p = 0.f;
  #pragma unroll
  for (int h = tid; h < Hc; h += 256)
    p = fmaf(v[h], fast_tanh(fmaf(sign, brow[h], arow[h])), p);
  __shared__ float buf4[4];
  p = block_sum256(p, buf4);
  if (tid == 0) S[(size_t)bm * Nc + n] = p;
}

// s[b,m,n] = sum_d Ym[b,m,d]*Xn[b,n,d]; grid (Nc, BM)
__global__ __launch_bounds__(256) void bilin_scores(const float* __restrict__ Ym,
                                                    const float* __restrict__ Xn,
                                                    float* __restrict__ S) {
  const int n = blockIdx.x;
  const int bm = blockIdx.y;
  const int b = bm >> 7;
  const float* yrow = Ym + (size_t)bm * Dc;
  const float* xrow = Xn + (size_t)(b * Nc + n) * Dc;
  const int tid = threadIdx.x;
  float p = 0.f;
  #pragma unroll
  for (int d = tid; d < Dc; d += 256) p = fmaf(yrow[d], xrow[d], p);
  __shared__ float buf4[4];
  p = block_sum256(p, buf4);
  if (tid == 0) S[(size_t)bm * Nc + n] = p;
}

// in-place softmax over last dim (=128); one row per block, 128 threads
__global__ __launch_bounds__(128) void softmax128(float* __restrict__ S) {
  const int row = blockIdx.x;
  const int tid = threadIdx.x;
  float x = S[(size_t)row * 128 + tid];
  __shared__ float mbuf[2], sbuf[2];
  float mx = x;
  #pragma unroll
  for (int o = 32; o; o >>= 1) mx = fmaxf(mx, __shfl_down(mx, o, 64));
  if ((tid & 63) == 0) mbuf[tid >> 6] = mx;
  __syncthreads();
  mx = fmaxf(mbuf[0], mbuf[1]);
  float e = __expf(x - mx);
  float sm = e;
  #pragma unroll
  for (int o = 32; o; o >>= 1) sm += __shfl_down(sm, o, 64);
  if ((tid & 63) == 0) sbuf[tid >> 6] = sm;
  __syncthreads();
  sm = sbuf[0] + sbuf[1];
  S[(size_t)row * 128 + tid] = e / sm;
}

#define FMA4(acc, s, v)                  \
  acc.x = fmaf(s, v.x, acc.x);           \
  acc.y = fmaf(s, v.y, acc.y);           \
  acc.z = fmaf(s, v.z, acc.z);           \
  acc.w = fmaf(s, v.w, acc.w)

// agg[b,m,d] = max(x1[b,m,d], qtc, qtb, qts, qtd, qtm); grid (BM), 256 threads x 4 d each
__global__ __launch_bounds__(256) void agg_max(const float* __restrict__ x0,
                                               const float* __restrict__ x1,
                                               const float* __restrict__ Sc,
                                               const float* __restrict__ Sb,
                                               const float* __restrict__ Sd1,
                                               const float* __restrict__ Sd2,
                                               const float* __restrict__ Sm,
                                               float* __restrict__ agg) {
  const int bm = blockIdx.x;
  const int b = bm >> 7;
  const int tid = threadIdx.x;
  __shared__ float w[5][128];
  if (tid < 128) {
    w[0][tid] = Sc[(size_t)bm * Nc + tid];
    w[1][tid] = Sb[(size_t)bm * Nc + tid];
    w[2][tid] = Sd1[(size_t)bm * Nc + tid];
    w[3][tid] = Sd2[(size_t)bm * Nc + tid];
    w[4][tid] = Sm[(size_t)bm * Nc + tid];
  }
  __syncthreads();
  const int d0 = tid * 4;
  float4 qc = {0, 0, 0, 0}, qb = {0, 0, 0, 0}, qs = {0, 0, 0, 0};
  float4 qd = {0, 0, 0, 0}, qm = {0, 0, 0, 0};
  const float* X0b = x0 + (size_t)b * Nc * Dc;
  const float* X1b = x1 + (size_t)b * Nc * Dc;
  for (int n = 0; n < Nc; n++) {
    float4 xv = *reinterpret_cast<const float4*>(&X0b[(size_t)n * Dc + d0]);
    float4 yv = *reinterpret_cast<const float4*>(&X1b[(size_t)n * Dc + d0]);
    float wc = w[0][n], wb = w[1][n], ws = w[2][n], wd = w[3][n], wm = w[4][n];
    FMA4(qc, wc, xv);  // concat att -> x0
    FMA4(qb, wb, xv);  // bilinear -> x0
    FMA4(qs, ws, xv);  // dot1 (x=x0) -> x0
    FMA4(qd, wd, yv);  // dot2 (x=x1) -> x1
    FMA4(qm, wm, xv);  // minus -> x0
  }
  float4 x1v = *reinterpret_cast<const float4*>(&x1[(size_t)bm * Dc + d0]);
  float4 r;
  r.x = fmaxf(x1v.x, fmaxf(fmaxf(qs.x, qc.x), fmaxf(fmaxf(qd.x, qb.x), qm.x)));
  r.y = fmaxf(x1v.y, fmaxf(fmaxf(qs.y, qc.y), fmaxf(fmaxf(qd.y, qb.y), qm.y)));
  r.z = fmaxf(x1v.z, fmaxf(fmaxf(qs.z, qc.z), fmaxf(fmaxf(qd.z, qb.z), qm.z)));
  r.w = fmaxf(x1v.w, fmaxf(fmaxf(qs.w, qc.w), fmaxf(fmaxf(qd.w, qb.w), qm.w)));
  *reinterpret_cast<float4*>(&agg[(size_t)bm * Dc + d0]) = r;
}

// u[d2] = sum_h Wp1[d2,h]*vp[h]; grid (2*Dc), 64 threads
__global__ __launch_bounds__(64) void compute_u(const float* __restrict__ Wp1,
                                                const float* __restrict__ vp,
                                                float* __restrict__ u) {
  const int d2 = blockIdx.x;
  const int tid = threadIdx.x;
  float p = 0.f;
  #pragma unroll
  for (int h = tid; h < Hc; h += 64) p = fmaf(Wp1[(size_t)d2 * Hc + h], vp[h], p);
  #pragma unroll
  for (int o = 32; o; o >>= 1) p += __shfl_down(p, o, 64);
  if (tid == 0) u[d2] = p;
}

// score[bm] = x1[bm,:].u[0:D] + agg[bm,:].u[D:2D]   (rq@Wp2 term is softmax-invariant)
__global__ __launch_bounds__(256) void final_scores(const float* __restrict__ x1,
                                                    const float* __restrict__ agg,
                                                    const float* __restrict__ u,
                                                    float* __restrict__ score) {
  const int bm = blockIdx.x;
  const int tid = threadIdx.x;
  float p = 0.f;
  #pragma unroll
  for (int d = tid; d < Dc; d += 256)
    p = fmaf(x1[(size_t)bm * Dc + d], u[d], fmaf(agg[(size_t)bm * Dc + d], u[Dc + d], p));
  __shared__ float buf4[4];
  p = block_sum256(p, buf4);
  if (tid == 0) score[bm] = p;
}

// out[b,j] = relu( sum_m sp[b,m]*(cat[b,m,:].Wpred[:,j]) + bpred[j] ); grid (B), 256 thr
__global__ __launch_bounds__(256) void final_out(const float* __restrict__ x1,
                                                 const float* __restrict__ agg,
                                                 const float* __restrict__ sp,
                                                 const float* __restrict__ Wpred,
                                                 const float* __restrict__ bpred,
                                                 float* __restrict__ out) {
  const int b = blockIdx.x;
  const int tid = threadIdx.x;
  __shared__ float spL[128];
  if (tid < 128) spL[tid] = sp[b * Nc + tid];
  __syncthreads();
  const int d2 = tid * 8;  // 256*8 = 2048, chunks never straddle the x1/agg boundary
  float w0[8], w1[8];
  #pragma unroll
  for (int i = 0; i < 8; i++) {
    w0[i] = Wpred[(size_t)(d2 + i) * 2 + 0];
    w1[i] = Wpred[(size_t)(d2 + i) * 2 + 1];
  }
  const float* src = (d2 < Dc) ? (x1 + (size_t)b * Nc * Dc + d2)
                               : (agg + (size_t)b * Nc * Dc + (d2 - Dc));
  float p0 = 0.f, p1 = 0.f;
  for (int m = 0; m < Nc; m++) {
    float s = spL[m];
    const float* r = src + (size_t)m * Dc;
    #pragma unroll
    for (int i = 0; i < 8; i++) {
      float sc = s * r[i];
      p0 = fmaf(sc, w0[i], p0);
      p1 = fmaf(sc, w1[i], p1);
    }
  }
  #pragma unroll
  for (int o = 32; o; o >>= 1) {
    p0 += __shfl_down(p0, o, 64);
    p1 += __shfl_down(p1, o, 64);
  }
  __shared__ float r0[4], r1[4];
  const int w = tid >> 6, lane = tid & 63;
  if (lane == 0) { r0[w] = p0; r1[w] = p1; }
  __syncthreads();
  if (tid == 0) {
    float q0 = r0[0] + r0[1] + r0[2] + r0[3] + bpred[0];
    float q1 = r1[0] + r1[1] + r1[2] + r1[3] + bpred[1];
    out[b * 2 + 0] = fmaxf(q0, 0.f);
    out[b * 2 + 1] = fmaxf(q1, 0.f);
  }
}

extern "C" void kernel_launch(void* const* d_in, const int* in_sizes, int n_in,
                              void* d_out, int out_size, void* d_ws, size_t ws_size,
                              hipStream_t stream) {
  const float* x0    = (const float*)d_in[0];
  const float* x1    = (const float*)d_in[1];
  const float* Wc1   = (const float*)d_in[2];
  const float* Wc2   = (const float*)d_in[3];
  const float* vc    = (const float*)d_in[4];
  const float* Wb    = (const float*)d_in[5];
  const float* Wd1   = (const float*)d_in[6];
  const float* vd1   = (const float*)d_in[7];
  const float* Wd2   = (const float*)d_in[8];
  const float* vd2   = (const float*)d_in[9];
  const float* Wm    = (const float*)d_in[10];
  const float* vm    = (const float*)d_in[11];
  // d_in[12]=Wq, d_in[13]=vq, d_in[15]=Wp2: provably dead (softmax shift-invariance)
  const float* Wp1   = (const float*)d_in[14];
  const float* vp    = (const float*)d_in[16];
  const float* Wpred = (const float*)d_in[17];
  const float* bpred = (const float*)d_in[18];
  float* out = (float*)d_out;

  float* ws = (float*)d_ws;
  float* ac     = ws;               // [B,N,H]  524288
  float* bcv    = ac + 524288;      // [B,N,H]
  float* am     = bcv + 524288;     // [B,N,H]
  float* bmv    = am + 524288;      // [B,N,H]
  float* xWb    = bmv + 524288;     // [B,N,D] 1048576
  float* sc     = xWb + 1048576;    // 5 contiguous score tensors [B,M,N] = 131072 each
  float* sb     = sc + 131072;
  float* sd1    = sb + 131072;
  float* sd2    = sd1 + 131072;
  float* smv    = sd2 + 131072;
  float* agg    = smv + 131072;     // [B,M,D] 1048576
  float* u      = agg + 1048576;    // [2D] 2048
  float* score2 = u + 2048;         // [B*M] 1024
  // total ~19.4 MB

  // --- projections ---
  gemm_rm<<<dim3(Hc / 64, BM / 64), 256, 0, stream>>>(x0, Wc1, ac, Dc, Hc);
  gemm_rm<<<dim3(Hc / 64, BM / 64), 256, 0, stream>>>(x1, Wc2, bcv, Dc, Hc);
  gemm_rm<<<dim3(Hc / 64, BM / 64), 256, 0, stream>>>(x0, Wm, am, Dc, Hc);
  gemm_rm<<<dim3(Hc / 64, BM / 64), 256, 0, stream>>>(x1, Wm, bmv, Dc, Hc);
  gemm_rm<<<dim3(Dc / 64, BM / 64), 256, 0, stream>>>(x0, Wb, xWb, Dc, Dc);

  // --- attention scores ---
  addtanh_scores<<<dim3(Nc, BM), 256, 0, stream>>>(ac, bcv, vc, 1.f, sc);
  addtanh_scores<<<dim3(Nc, BM), 256, 0, stream>>>(am, bmv, vm, -1.f, smv);
  bilin_scores<<<dim3(Nc, BM), 256, 0, stream>>>(x1, xWb, sb);
  hipMemsetAsync(sd1, 0, 2 * 131072 * sizeof(float), stream);  // sd1+sd2 contiguous
  dot_scores<<<dim3(Hc / 64, Nc / 64, BM), 256, 0, stream>>>(x0, x1, Wd1, vd1, sd1);
  dot_scores<<<dim3(Hc / 64, Nc / 64, BM), 256, 0, stream>>>(x1, x0, Wd2, vd2, sd2);

  // --- softmax over n for all 5 score tensors (contiguous rows) ---
  softmax128<<<5 * BM, 128, 0, stream>>>(sc);

  // --- weighted sums + elementwise max ---
  agg_max<<<BM, 256, 0, stream>>>(x0, x1, sc, sb, sd1, sd2, smv, agg);

  // --- aggregation (rq path dropped: softmax shift-invariant; Wp1@vp prefolded) ---
  compute_u<<<2 * Dc, 64, 0, stream>>>(Wp1, vp, u);
  final_scores<<<BM, 256, 0, stream>>>(x1, agg, u, score2);
  softmax128<<<Bc, 128, 0, stream>>>(score2);
  final_out<<<Bc, 256, 0, stream>>>(x1, agg, score2, Wpred, bpred, out);
}

// Round 2
// 1348.149 us; speedup vs baseline: 3.8793x; 3.8793x over previous
//
#include <hip/hip_runtime.h>
#include <hip/hip_bf16.h>

// Shapes (fixed by the reference): B=8, N=M=128, D=1024, H=512
static constexpr int Bc = 8, Nc = 128, Dc = 1024, Hc = 512;
static constexpr int BM = Bc * Nc;  // 1024

typedef short short8 __attribute__((ext_vector_type(8)));
typedef float floatx4 __attribute__((ext_vector_type(4)));

__device__ __forceinline__ float fast_tanh(float x) {
  x = fminf(fmaxf(x, -15.f), 15.f);
  float e = __expf(2.f * x);
  return (e - 1.f) / (e + 1.f);
}

__device__ __forceinline__ ushort f2bf(float f) {  // round-to-nearest-even
  unsigned u = __float_as_uint(f);
  u += 0x7FFFu + ((u >> 16) & 1u);
  return (ushort)(u >> 16);
}

// sum over 256-thread block; result broadcast to all threads
__device__ __forceinline__ float block_sum256(float v, float* buf4) {
  #pragma unroll
  for (int o = 32; o; o >>= 1) v += __shfl_down(v, o, 64);
  const int w = threadIdx.x >> 6, lane = threadIdx.x & 63;
  if (lane == 0) buf4[w] = v;
  __syncthreads();
  return buf4[0] + buf4[1] + buf4[2] + buf4[3];
}

// C[r,j] = sum_k A[r,k]*W[k,j]; R multiple of 64 (grid.y), J multiple of 64, K multiple of 16
__global__ __launch_bounds__(256) void gemm_rm(const float* __restrict__ A,
                                               const float* __restrict__ W,
                                               float* __restrict__ C,
                                               int K, int J) {
  __shared__ __align__(16) float As[16][64];
  __shared__ __align__(16) float Ws[16][64];
  const int tid = threadIdx.x;
  const int tx = tid & 15, ty = tid >> 4;
  const int rowBase = blockIdx.y * 64;
  const int colBase = blockIdx.x * 64;
  float acc[4][4] = {};
  for (int k0 = 0; k0 < K; k0 += 16) {
    #pragma unroll
    for (int i = 0; i < 4; i++) {
      int idx = tid + i * 256;
      int m = idx >> 4, k = idx & 15;
      As[k][m] = A[(size_t)(rowBase + m) * K + k0 + k];
    }
    #pragma unroll
    for (int i = 0; i < 4; i++) {
      int idx = tid + i * 256;
      int k = idx >> 6, j = idx & 63;
      Ws[k][j] = W[(size_t)(k0 + k) * J + colBase + j];
    }
    __syncthreads();
    #pragma unroll
    for (int k = 0; k < 16; k++) {
      float4 av = *reinterpret_cast<const float4*>(&As[k][ty * 4]);
      float4 wv = *reinterpret_cast<const float4*>(&Ws[k][tx * 4]);
      float a_[4] = {av.x, av.y, av.z, av.w};
      float w_[4] = {wv.x, wv.y, wv.z, wv.w};
      #pragma unroll
      for (int i = 0; i < 4; i++)
        #pragma unroll
        for (int j = 0; j < 4; j++)
          acc[i][j] = fmaf(a_[i], w_[j], acc[i][j]);
    }
    __syncthreads();
  }
  #pragma unroll
  for (int i = 0; i < 4; i++)
    #pragma unroll
    for (int j = 0; j < 4; j++)
      C[(size_t)(rowBase + ty * 4 + i) * J + colBase + tx * 4 + j] = acc[i][j];
}

// Transpose + convert W [D,H] fp32 -> WT [H,D] bf16. grid (D/64, H/64), 256 thr.
__global__ __launch_bounds__(256) void conv_transpose_w(const float* __restrict__ W,
                                                        ushort* __restrict__ WT) {
  __shared__ float tile[64][65];  // 65: conflict-free column reads
  const int d0 = blockIdx.x * 64;
  const int h0 = blockIdx.y * 64;
  const int tid = threadIdx.x;
  #pragma unroll
  for (int i = 0; i < 16; i++) {
    int idx = tid + i * 256;
    int dd = idx >> 6, hh = idx & 63;
    tile[dd][hh] = W[(size_t)(d0 + dd) * Hc + h0 + hh];
  }
  __syncthreads();
  #pragma unroll
  for (int i = 0; i < 16; i++) {
    int idx = tid + i * 256;
    int hh = idx >> 6, dd = idx & 63;
    WT[(size_t)(h0 + hh) * Dc + d0 + dd] = f2bf(tile[dd][hh]);
  }
}

// s[b,m,n] += sum_h v[h]*tanh( sum_d X[b,n,d]*Y[b,m,d]*Wd[d,h] )  via bf16 MFMA.
// Block: one (b,m), all 128 n, one 64-wide h tile, K=1024. grid (Hc/64, BM).
// WdT is bf16 [H, D] (pre-transposed). S must be pre-zeroed (atomics over h-tiles).
__global__ __launch_bounds__(256) void dot_scores_mfma(const float* __restrict__ X,
                                                       const float* __restrict__ Y,
                                                       const ushort* __restrict__ WdT,
                                                       const float* __restrict__ v,
                                                       float* __restrict__ S) {
  const int bm = blockIdx.y;
  const int b = bm >> 7;
  const int hBase = blockIdx.x * 64;
  const int tid = threadIdx.x;
  const int wave = tid >> 6, lane = tid & 63;
  const int quad = lane >> 4, l15 = lane & 15;

  // rows padded to 40 ushorts = 80 B (16B-aligned chunks, <=2-way bank aliasing)
  __shared__ __align__(16) ushort As[128][40];
  __shared__ __align__(16) ushort Bs[64][40];
  __shared__ __align__(16) float yl[Dc];
  __shared__ float red[128][17];

  for (int i = tid; i < Dc; i += 256) yl[i] = Y[(size_t)bm * Dc + i];

  float vv[4];
  #pragma unroll
  for (int hf = 0; hf < 4; hf++) vv[hf] = v[hBase + hf * 16 + l15];

  floatx4 acc[2][4];
  #pragma unroll
  for (int i = 0; i < 2; i++)
    #pragma unroll
    for (int j = 0; j < 4; j++) acc[i][j] = (floatx4){0.f, 0.f, 0.f, 0.f};

  const float* Xb = X + (size_t)b * Nc * Dc;
  const int nA = tid >> 2;          // 0..63 (row; second row is +64)
  const int kqA = (tid & 3) * 8;    // 8-elem chunk within the 32-wide k-slab
  const int hB = tid >> 2;          // 0..63
  __syncthreads();                  // yl ready

  for (int k0 = 0; k0 < Dc; k0 += 32) {
    // stage A: As[n][k] = bf16( X[b,n,k0+k] * y[k0+k] ), 2 rows/thread
    float4 ylo = *reinterpret_cast<const float4*>(&yl[k0 + kqA]);
    float4 yhi = *reinterpret_cast<const float4*>(&yl[k0 + kqA + 4]);
    #pragma unroll
    for (int rr = 0; rr < 2; rr++) {
      const int n = nA + rr * 64;
      const float* src = Xb + (size_t)n * Dc + k0 + kqA;
      float4 f0 = *reinterpret_cast<const float4*>(src);
      float4 f1 = *reinterpret_cast<const float4*>(src + 4);
      uint4 o;
      o.x = (unsigned)f2bf(f0.x * ylo.x) | ((unsigned)f2bf(f0.y * ylo.y) << 16);
      o.y = (unsigned)f2bf(f0.z * ylo.z) | ((unsigned)f2bf(f0.w * ylo.w) << 16);
      o.z = (unsigned)f2bf(f1.x * yhi.x) | ((unsigned)f2bf(f1.y * yhi.y) << 16);
      o.w = (unsigned)f2bf(f1.z * yhi.z) | ((unsigned)f2bf(f1.w * yhi.w) << 16);
      *reinterpret_cast<uint4*>(&As[n][kqA]) = o;
    }
    // stage B: Bs[h][k] = WdT[hBase+h][k0+k]
    *reinterpret_cast<uint4*>(&Bs[hB][kqA]) =
        *reinterpret_cast<const uint4*>(&WdT[(size_t)(hBase + hB) * Dc + k0 + kqA]);
    __syncthreads();
    short8 a0 = *reinterpret_cast<const short8*>(&As[wave * 32 + l15][quad * 8]);
    short8 a1 = *reinterpret_cast<const short8*>(&As[wave * 32 + 16 + l15][quad * 8]);
    #pragma unroll
    for (int hf = 0; hf < 4; hf++) {
      short8 bf = *reinterpret_cast<const short8*>(&Bs[hf * 16 + l15][quad * 8]);
      acc[0][hf] = __builtin_amdgcn_mfma_f32_16x16x32_bf16(a0, bf, acc[0][hf], 0, 0, 0);
      acc[1][hf] = __builtin_amdgcn_mfma_f32_16x16x32_bf16(a1, bf, acc[1][hf], 0, 0, 0);
    }
    __syncthreads();
  }

  // epilogue: p[n] = sum over this lane's 4 h-cols of v[h]*tanh(z)
  #pragma unroll
  for (int nf = 0; nf < 2; nf++)
    #pragma unroll
    for (int r = 0; r < 4; r++) {
      float p = 0.f;
      #pragma unroll
      for (int hf = 0; hf < 4; hf++) p = fmaf(vv[hf], fast_tanh(acc[nf][hf][r]), p);
      red[wave * 32 + nf * 16 + quad * 4 + r][l15] = p;
    }
  __syncthreads();
  if (tid < 128) {
    float s = 0.f;
    #pragma unroll
    for (int j = 0; j < 16; j++) s += red[tid][j];
    atomicAdd(&S[(size_t)bm * Nc + tid], s);
  }
}

// s[b,m,n] = sum_h v[h]*tanh(An[b,n,h] + sign*Bm[b,m,h]); grid (Nc, BM)
__global__ __launch_bounds__(256) void addtanh_scores(const float* __restrict__ An,
                                                      const float* __restrict__ Bm,
                                                      const float* __restrict__ v,
                                                      float sign,
                                                      float* __restrict__ S) {
  const int n = blockIdx.x;
  const int bm = blockIdx.y;
  const int b = bm >> 7;
  const float* arow = An + (size_t)(b * Nc + n) * Hc;
  const float* brow = Bm + (size_t)bm * Hc;
  const int tid = threadIdx.x;
  float p = 0.f;
  #pragma unroll
  for (int h = tid; h < Hc; h += 256)
    p = fmaf(v[h], fast_tanh(fmaf(sign, brow[h], arow[h])), p);
  __shared__ float buf4[4];
  p = block_sum256(p, buf4);
  if (tid == 0) S[(size_t)bm * Nc + n] = p;
}

// s[b,m,n] = sum_d Ym[b,m,d]*Xn[b,n,d]; grid (Nc, BM)
__global__ __launch_bounds__(256) void bilin_scores(const float* __restrict__ Ym,
                                                    const float* __restrict__ Xn,
                                                    float* __restrict__ S) {
  const int n = blockIdx.x;
  const int bm = blockIdx.y;
  const int b = bm >> 7;
  const float* yrow = Ym + (size_t)bm * Dc;
  const float* xrow = Xn + (size_t)(b * Nc + n) * Dc;
  const int tid = threadIdx.x;
  float p = 0.f;
  #pragma unroll
  for (int d = tid; d < Dc; d += 256) p = fmaf(yrow[d], xrow[d], p);
  __shared__ float buf4[4];
  p = block_sum256(p, buf4);
  if (tid == 0) S[(size_t)bm * Nc + n] = p;
}

// in-place softmax over last dim (=128); one row per block, 128 threads
__global__ __launch_bounds__(128) void softmax128(float* __restrict__ S) {
  const int row = blockIdx.x;
  const int tid = threadIdx.x;
  float x = S[(size_t)row * 128 + tid];
  __shared__ float mbuf[2], sbuf[2];
  float mx = x;
  #pragma unroll
  for (int o = 32; o; o >>= 1) mx = fmaxf(mx, __shfl_down(mx, o, 64));
  if ((tid & 63) == 0) mbuf[tid >> 6] = mx;
  __syncthreads();
  mx = fmaxf(mbuf[0], mbuf[1]);
  float e = __expf(x - mx);
  float sm = e;
  #pragma unroll
  for (int o = 32; o; o >>= 1) sm += __shfl_down(sm, o, 64);
  if ((tid & 63) == 0) sbuf[tid >> 6] = sm;
  __syncthreads();
  sm = sbuf[0] + sbuf[1];
  S[(size_t)row * 128 + tid] = e / sm;
}

#define FMA4(acc, s, v)                  \
  acc.x = fmaf(s, v.x, acc.x);           \
  acc.y = fmaf(s, v.y, acc.y);           \
  acc.z = fmaf(s, v.z, acc.z);           \
  acc.w = fmaf(s, v.w, acc.w)

// agg[b,m,d] = max(x1[b,m,d], qtc, qtb, qts, qtd, qtm); grid (BM), 256 threads x 4 d each
__global__ __launch_bounds__(256) void agg_max(const float* __restrict__ x0,
                                               const float* __restrict__ x1,
                                               const float* __restrict__ Sc,
                                               const float* __restrict__ Sb,
                                               const float* __restrict__ Sd1,
                                               const float* __restrict__ Sd2,
                                               const float* __restrict__ Sm,
                                               float* __restrict__ agg) {
  const int bm = blockIdx.x;
  const int b = bm >> 7;
  const int tid = threadIdx.x;
  __shared__ float w[5][128];
  if (tid < 128) {
    w[0][tid] = Sc[(size_t)bm * Nc + tid];
    w[1][tid] = Sb[(size_t)bm * Nc + tid];
    w[2][tid] = Sd1[(size_t)bm * Nc + tid];
    w[3][tid] = Sd2[(size_t)bm * Nc + tid];
    w[4][tid] = Sm[(size_t)bm * Nc + tid];
  }
  __syncthreads();
  const int d0 = tid * 4;
  float4 qc = {0, 0, 0, 0}, qb = {0, 0, 0, 0}, qs = {0, 0, 0, 0};
  float4 qd = {0, 0, 0, 0}, qm = {0, 0, 0, 0};
  const float* X0b = x0 + (size_t)b * Nc * Dc;
  const float* X1b = x1 + (size_t)b * Nc * Dc;
  for (int n = 0; n < Nc; n++) {
    float4 xv = *reinterpret_cast<const float4*>(&X0b[(size_t)n * Dc + d0]);
    float4 yv = *reinterpret_cast<const float4*>(&X1b[(size_t)n * Dc + d0]);
    float wc = w[0][n], wb = w[1][n], ws = w[2][n], wd = w[3][n], wm = w[4][n];
    FMA4(qc, wc, xv);  // concat att -> x0
    FMA4(qb, wb, xv);  // bilinear -> x0
    FMA4(qs, ws, xv);  // dot1 (x=x0) -> x0
    FMA4(qd, wd, yv);  // dot2 (x=x1) -> x1
    FMA4(qm, wm, xv);  // minus -> x0
  }
  float4 x1v = *reinterpret_cast<const float4*>(&x1[(size_t)bm * Dc + d0]);
  float4 r;
  r.x = fmaxf(x1v.x, fmaxf(fmaxf(qs.x, qc.x), fmaxf(fmaxf(qd.x, qb.x), qm.x)));
  r.y = fmaxf(x1v.y, fmaxf(fmaxf(qs.y, qc.y), fmaxf(fmaxf(qd.y, qb.y), qm.y)));
  r.z = fmaxf(x1v.z, fmaxf(fmaxf(qs.z, qc.z), fmaxf(fmaxf(qd.z, qb.z), qm.z)));
  r.w = fmaxf(x1v.w, fmaxf(fmaxf(qs.w, qc.w), fmaxf(fmaxf(qd.w, qb.w), qm.w)));
  *reinterpret_cast<float4*>(&agg[(size_t)bm * Dc + d0]) = r;
}

// u[d2] = sum_h Wp1[d2,h]*vp[h]; grid (2*Dc), 64 threads
__global__ __launch_bounds__(64) void compute_u(const float* __restrict__ Wp1,
                                                const float* __restrict__ vp,
                                                float* __restrict__ u) {
  const int d2 = blockIdx.x;
  const int tid = threadIdx.x;
  float p = 0.f;
  #pragma unroll
  for (int h = tid; h < Hc; h += 64) p = fmaf(Wp1[(size_t)d2 * Hc + h], vp[h], p);
  #pragma unroll
  for (int o = 32; o; o >>= 1) p += __shfl_down(p, o, 64);
  if (tid == 0) u[d2] = p;
}

// score[bm] = x1[bm,:].u[0:D] + agg[bm,:].u[D:2D]   (rq@Wp2 term is softmax-invariant)
__global__ __launch_bounds__(256) void final_scores(const float* __restrict__ x1,
                                                    const float* __restrict__ agg,
                                                    const float* __restrict__ u,
                                                    float* __restrict__ score) {
  const int bm = blockIdx.x;
  const int tid = threadIdx.x;
  float p = 0.f;
  #pragma unroll
  for (int d = tid; d < Dc; d += 256)
    p = fmaf(x1[(size_t)bm * Dc + d], u[d], fmaf(agg[(size_t)bm * Dc + d], u[Dc + d], p));
  __shared__ float buf4[4];
  p = block_sum256(p, buf4);
  if (tid == 0) score[bm] = p;
}

// out[b,j] = relu( sum_m sp[b,m]*(cat[b,m,:].Wpred[:,j]) + bpred[j] ); grid (B), 256 thr
__global__ __launch_bounds__(256) void final_out(const float* __restrict__ x1,
                                                 const float* __restrict__ agg,
                                                 const float* __restrict__ sp,
                                                 const float* __restrict__ Wpred,
                                                 const float* __restrict__ bpred,
                                                 float* __restrict__ out) {
  const int b = blockIdx.x;
  const int tid = threadIdx.x;
  __shared__ float spL[128];
  if (tid < 128) spL[tid] = sp[b * Nc + tid];
  __syncthreads();
  const int d2 = tid * 8;  // 256*8 = 2048, chunks never straddle the x1/agg boundary
  float w0[8], w1[8];
  #pragma unroll
  for (int i = 0; i < 8; i++) {
    w0[i] = Wpred[(size_t)(d2 + i) * 2 + 0];
    w1[i] = Wpred[(size_t)(d2 + i) * 2 + 1];
  }
  const float* src = (d2 < Dc) ? (x1 + (size_t)b * Nc * Dc + d2)
                               : (agg + (size_t)b * Nc * Dc + (d2 - Dc));
  float p0 = 0.f, p1 = 0.f;
  for (int m = 0; m < Nc; m++) {
    float s = spL[m];
    const float* r = src + (size_t)m * Dc;
    #pragma unroll
    for (int i = 0; i < 8; i++) {
      float sc = s * r[i];
      p0 = fmaf(sc, w0[i], p0);
      p1 = fmaf(sc, w1[i], p1);
    }
  }
  #pragma unroll
  for (int o = 32; o; o >>= 1) {
    p0 += __shfl_down(p0, o, 64);
    p1 += __shfl_down(p1, o, 64);
  }
  __shared__ float r0[4], r1[4];
  const int w = tid >> 6, lane = tid & 63;
  if (lane == 0) { r0[w] = p0; r1[w] = p1; }
  __syncthreads();
  if (tid == 0) {
    float q0 = r0[0] + r0[1] + r0[2] + r0[3] + bpred[0];
    float q1 = r1[0] + r1[1] + r1[2] + r1[3] + bpred[1];
    out[b * 2 + 0] = fmaxf(q0, 0.f);
    out[b * 2 + 1] = fmaxf(q1, 0.f);
  }
}

extern "C" void kernel_launch(void* const* d_in, const int* in_sizes, int n_in,
                              void* d_out, int out_size, void* d_ws, size_t ws_size,
                              hipStream_t stream) {
  const float* x0    = (const float*)d_in[0];
  const float* x1    = (const float*)d_in[1];
  const float* Wc1   = (const float*)d_in[2];
  const float* Wc2   = (const float*)d_in[3];
  const float* vc    = (const float*)d_in[4];
  const float* Wb    = (const float*)d_in[5];
  const float* Wd1   = (const float*)d_in[6];
  const float* vd1   = (const float*)d_in[7];
  const float* Wd2   = (const float*)d_in[8];
  const float* vd2   = (const float*)d_in[9];
  const float* Wm    = (const float*)d_in[10];
  const float* vm    = (const float*)d_in[11];
  // d_in[12]=Wq, d_in[13]=vq, d_in[15]=Wp2: provably dead (softmax shift-invariance)
  const float* Wp1   = (const float*)d_in[14];
  const float* vp    = (const float*)d_in[16];
  const float* Wpred = (const float*)d_in[17];
  const float* bpred = (const float*)d_in[18];
  float* out = (float*)d_out;

  float* ws = (float*)d_ws;
  float* ac     = ws;               // [B,N,H]  524288
  float* bcv    = ac + 524288;      // [B,N,H]
  float* am     = bcv + 524288;     // [B,N,H]
  float* bmv    = am + 524288;      // [B,N,H]
  float* xWb    = bmv + 524288;     // [B,N,D] 1048576
  float* sc     = xWb + 1048576;    // 5 contiguous score tensors [B,M,N] = 131072 each
  float* sb     = sc + 131072;
  float* sd1    = sb + 131072;
  float* sd2    = sd1 + 131072;
  float* smv    = sd2 + 131072;
  float* agg    = smv + 131072;     // [B,M,D] 1048576
  float* u      = agg + 1048576;    // [2D] 2048
  float* score2 = u + 2048;         // [B*M] 1024
  ushort* wdT1  = (ushort*)(score2 + 1024);   // [H,D] bf16, 524288 ushorts
  ushort* wdT2  = wdT1 + 524288;              // [H,D] bf16
  // total ~21.5 MB

  // --- weight prep for MFMA path ---
  conv_transpose_w<<<dim3(Dc / 64, Hc / 64), 256, 0, stream>>>(Wd1, wdT1);
  conv_transpose_w<<<dim3(Dc / 64, Hc / 64), 256, 0, stream>>>(Wd2, wdT2);

  // --- projections ---
  gemm_rm<<<dim3(Hc / 64, BM / 64), 256, 0, stream>>>(x0, Wc1, ac, Dc, Hc);
  gemm_rm<<<dim3(Hc / 64, BM / 64), 256, 0, stream>>>(x1, Wc2, bcv, Dc, Hc);
  gemm_rm<<<dim3(Hc / 64, BM / 64), 256, 0, stream>>>(x0, Wm, am, Dc, Hc);
  gemm_rm<<<dim3(Hc / 64, BM / 64), 256, 0, stream>>>(x1, Wm, bmv, Dc, Hc);
  gemm_rm<<<dim3(Dc / 64, BM / 64), 256, 0, stream>>>(x0, Wb, xWb, Dc, Dc);

  // --- attention scores ---
  addtanh_scores<<<dim3(Nc, BM), 256, 0, stream>>>(ac, bcv, vc, 1.f, sc);
  addtanh_scores<<<dim3(Nc, BM), 256, 0, stream>>>(am, bmv, vm, -1.f, smv);
  bilin_scores<<<dim3(Nc, BM), 256, 0, stream>>>(x1, xWb, sb);
  hipMemsetAsync(sd1, 0, 2 * 131072 * sizeof(float), stream);  // sd1+sd2 contiguous
  dot_scores_mfma<<<dim3(Hc / 64, BM), 256, 0, stream>>>(x0, x1, wdT1, vd1, sd1);
  dot_scores_mfma<<<dim3(Hc / 64, BM), 256, 0, stream>>>(x1, x0, wdT2, vd2, sd2);

  // --- softmax over n for all 5 score tensors (contiguous rows) ---
  softmax128<<<5 * BM, 128, 0, stream>>>(sc);

  // --- weighted sums + elementwise max ---
  agg_max<<<BM, 256, 0, stream>>>(x0, x1, sc, sb, sd1, sd2, smv, agg);

  // --- aggregation (rq path dropped: softmax shift-invariant; Wp1@vp prefolded) ---
  compute_u<<<2 * Dc, 64, 0, stream>>>(Wp1, vp, u);
  final_scores<<<BM, 256, 0, stream>>>(x1, agg, u, score2);
  softmax128<<<Bc, 128, 0, stream>>>(score2);
  final_out<<<Bc, 256, 0, stream>>>(x1, agg, score2, Wpred, bpred, out);
}

// Round 4
// 1169.353 us; speedup vs baseline: 4.4725x; 1.1529x over previous
//
#include <hip/hip_runtime.h>
#include <hip/hip_bf16.h>

// Shapes (fixed by the reference): B=8, N=M=128, D=1024, H=512
static constexpr int Bc = 8, Nc = 128, Dc = 1024, Hc = 512;
static constexpr int BM = Bc * Nc;  // 1024

typedef short short8 __attribute__((ext_vector_type(8)));
typedef float floatx4 __attribute__((ext_vector_type(4)));

__device__ __forceinline__ float fast_tanh(float x) {
  x = fminf(fmaxf(x, -15.f), 15.f);
  float e = __expf(2.f * x);
  return (e - 1.f) / (e + 1.f);
}

__device__ __forceinline__ ushort f2bf(float f) {  // round-to-nearest-even
  unsigned u = __float_as_uint(f);
  u += 0x7FFFu + ((u >> 16) & 1u);
  return (ushort)(u >> 16);
}

__device__ __forceinline__ unsigned pk2(float a, float b) {  // packed bf16 pair (RNE)
  return (unsigned)f2bf(a) | ((unsigned)f2bf(b) << 16);
}

// sum over 256-thread block; result broadcast to all threads
__device__ __forceinline__ float block_sum256(float v, float* buf4) {
  #pragma unroll
  for (int o = 32; o; o >>= 1) v += __shfl_down(v, o, 64);
  const int w = threadIdx.x >> 6, lane = threadIdx.x & 63;
  if (lane == 0) buf4[w] = v;
  __syncthreads();
  return buf4[0] + buf4[1] + buf4[2] + buf4[3];
}

// C[r,j] = sum_k A[r,k]*W[k,j]; R multiple of 64 (grid.y), J multiple of 64, K multiple of 16
__global__ __launch_bounds__(256) void gemm_rm(const float* __restrict__ A,
                                               const float* __restrict__ W,
                                               float* __restrict__ C,
                                               int K, int J) {
  __shared__ __align__(16) float As[16][64];
  __shared__ __align__(16) float Ws[16][64];
  const int tid = threadIdx.x;
  const int tx = tid & 15, ty = tid >> 4;
  const int rowBase = blockIdx.y * 64;
  const int colBase = blockIdx.x * 64;
  float acc[4][4] = {};
  for (int k0 = 0; k0 < K; k0 += 16) {
    #pragma unroll
    for (int i = 0; i < 4; i++) {
      int idx = tid + i * 256;
      int m = idx >> 4, k = idx & 15;
      As[k][m] = A[(size_t)(rowBase + m) * K + k0 + k];
    }
    #pragma unroll
    for (int i = 0; i < 4; i++) {
      int idx = tid + i * 256;
      int k = idx >> 6, j = idx & 63;
      Ws[k][j] = W[(size_t)(k0 + k) * J + colBase + j];
    }
    __syncthreads();
    #pragma unroll
    for (int k = 0; k < 16; k++) {
      float4 av = *reinterpret_cast<const float4*>(&As[k][ty * 4]);
      float4 wv = *reinterpret_cast<const float4*>(&Ws[k][tx * 4]);
      float a_[4] = {av.x, av.y, av.z, av.w};
      float w_[4] = {wv.x, wv.y, wv.z, wv.w};
      #pragma unroll
      for (int i = 0; i < 4; i++)
        #pragma unroll
        for (int j = 0; j < 4; j++)
          acc[i][j] = fmaf(a_[i], w_[j], acc[i][j]);
    }
    __syncthreads();
  }
  #pragma unroll
  for (int i = 0; i < 4; i++)
    #pragma unroll
    for (int j = 0; j < 4; j++)
      C[(size_t)(rowBase + ty * 4 + i) * J + colBase + tx * 4 + j] = acc[i][j];
}

// Transpose + convert W [D,H] fp32 -> WT [H,D] bf16. grid (D/64, H/64), 256 thr.
__global__ __launch_bounds__(256) void conv_transpose_w(const float* __restrict__ W,
                                                        ushort* __restrict__ WT) {
  __shared__ float tile[64][65];  // 65: conflict-free column reads
  const int d0 = blockIdx.x * 64;
  const int h0 = blockIdx.y * 64;
  const int tid = threadIdx.x;
  #pragma unroll
  for (int i = 0; i < 16; i++) {
    int idx = tid + i * 256;
    int dd = idx >> 6, hh = idx & 63;
    tile[dd][hh] = W[(size_t)(d0 + dd) * Hc + h0 + hh];
  }
  __syncthreads();
  #pragma unroll
  for (int i = 0; i < 16; i++) {
    int idx = tid + i * 256;
    int hh = idx >> 6, dd = idx & 63;
    WT[(size_t)(h0 + hh) * Dc + d0 + dd] = f2bf(tile[dd][hh]);
  }
}

// s[b,m,n] += sum_h v[h]*tanh( sum_d X[b,n,d]*Y[b,m,d]*Wd[d,h] )  via bf16 MFMA.
// Block: one (b,m), ALL 128 n, one 256-wide h half, K=1024. grid (2, BM).
// 4 waves in 2x2: each wave owns a 64n x 128h tile = 4x8 16x16x32 frags (128 AGPR).
// WdT is bf16 [H, D] (pre-transposed). S must be pre-zeroed (atomics over 2 h-halves).
__global__ __launch_bounds__(256, 2) void dot_scores_mfma2(const float* __restrict__ X,
                                                           const float* __restrict__ Y,
                                                           const ushort* __restrict__ WdT,
                                                           const float* __restrict__ v,
                                                           float* __restrict__ S) {
  const int bm = blockIdx.y;
  const int b = bm >> 7;
  const int hBase = blockIdx.x * 256;
  const int tid = threadIdx.x;
  const int wave = tid >> 6, lane = tid & 63;
  const int quad = lane >> 4, l15 = lane & 15;
  const int wn = wave & 1, wh = wave >> 1;  // wave tile: n in [wn*64,+64), h in [wh*128,+128)

  // rows padded to 40 ushorts = 80 B (16B-aligned b128 chunks; 20-dword stride -> 2-way = free)
  __shared__ __align__(16) ushort As[128][40];   // 10.0 KB  A-tile: bf16(x[n,k]*y[m,k])
  __shared__ __align__(16) ushort Bs[256][40];   // 20.0 KB  B-tile: WdT rows
  __shared__ __align__(16) float yl[Dc];         //  4.0 KB  y row (m)
  __shared__ float red[128][33];                 // 16.9 KB  epilogue reduction

  for (int i = tid; i < Dc; i += 256) yl[i] = Y[(size_t)bm * Dc + i];

  floatx4 acc[4][8];
  #pragma unroll
  for (int i = 0; i < 4; i++)
    #pragma unroll
    for (int j = 0; j < 8; j++) acc[i][j] = (floatx4){0.f, 0.f, 0.f, 0.f};

  const float* Xb = X + (size_t)b * Nc * Dc;
  const int nSt = tid >> 2;          // 0..63 (A/B staging row; +64 for second half)
  const int kSt4 = (tid & 3) * 4;    // A: 4-float chunk
  const int kSt8 = (tid & 3) * 8;    // B: 8-bf16 chunk
  __syncthreads();                   // yl ready

  for (int k0 = 0; k0 < Dc; k0 += 32) {
    // stage A: As[n][k] = bf16( X[b,n,k0+k] * y[k0+k] ); 4 units of 4 elems per thread
    #pragma unroll
    for (int u = 0; u < 4; u++) {
      const int n = (u >> 1) * 64 + nSt;
      const int kc = (u & 1) * 16 + kSt4;
      float4 xv = *reinterpret_cast<const float4*>(&Xb[(size_t)n * Dc + k0 + kc]);
      float4 yv = *reinterpret_cast<const float4*>(&yl[k0 + kc]);
      uint2 o;
      o.x = pk2(xv.x * yv.x, xv.y * yv.y);
      o.y = pk2(xv.z * yv.z, xv.w * yv.w);
      *reinterpret_cast<uint2*>(&As[n][kc]) = o;
    }
    // stage B: Bs[h][k] = WdT[hBase+h][k0+k]; 4 rows of 64 per pass
    #pragma unroll
    for (int r = 0; r < 4; r++) {
      const int h = r * 64 + nSt;
      *reinterpret_cast<uint4*>(&Bs[h][kSt8]) =
          *reinterpret_cast<const uint4*>(&WdT[(size_t)(hBase + h) * Dc + k0 + kSt8]);
    }
    __syncthreads();
    short8 af[4], bf[8];
    #pragma unroll
    for (int i = 0; i < 4; i++)
      af[i] = *reinterpret_cast<const short8*>(&As[wn * 64 + i * 16 + l15][quad * 8]);
    #pragma unroll
    for (int j = 0; j < 8; j++)
      bf[j] = *reinterpret_cast<const short8*>(&Bs[wh * 128 + j * 16 + l15][quad * 8]);
    #pragma unroll
    for (int i = 0; i < 4; i++)
      #pragma unroll
      for (int j = 0; j < 8; j++)
        acc[i][j] = __builtin_amdgcn_mfma_f32_16x16x32_bf16(af[i], bf[j], acc[i][j], 0, 0, 0);
    __syncthreads();
  }

  // epilogue: p[n] = sum over this wave's 128 h of v[h]*tanh(z[n,h])
  float vv[8];
  #pragma unroll
  for (int j = 0; j < 8; j++) vv[j] = v[hBase + wh * 128 + j * 16 + l15];
  #pragma unroll
  for (int i = 0; i < 4; i++)
    #pragma unroll
    for (int r = 0; r < 4; r++) {
      float p = 0.f;
      #pragma unroll
      for (int j = 0; j < 8; j++) p = fmaf(vv[j], fast_tanh(acc[i][j][r]), p);
      red[wn * 64 + i * 16 + quad * 4 + r][wh * 16 + l15] = p;
    }
  __syncthreads();
  if (tid < 128) {
    float s = 0.f;
    #pragma unroll
    for (int c = 0; c < 32; c++) s += red[tid][c];
    atomicAdd(&S[(size_t)bm * Nc + tid], s);
  }
}

// s[b,m,n] = sum_h v[h]*tanh(An[b,n,h] + sign*Bm[b,m,h]); grid (Nc, BM)
__global__ __launch_bounds__(256) void addtanh_scores(const float* __restrict__ An,
                                                      const float* __restrict__ Bm,
                                                      const float* __restrict__ v,
                                                      float sign,
                                                      float* __restrict__ S) {
  const int n = blockIdx.x;
  const int bm = blockIdx.y;
  const int b = bm >> 7;
  const float* arow = An + (size_t)(b * Nc + n) * Hc;
  const float* brow = Bm + (size_t)bm * Hc;
  const int tid = threadIdx.x;
  float p = 0.f;
  #pragma unroll
  for (int h = tid; h < Hc; h += 256)
    p = fmaf(v[h], fast_tanh(fmaf(sign, brow[h], arow[h])), p);
  __shared__ float buf4[4];
  p = block_sum256(p, buf4);
  if (tid == 0) S[(size_t)bm * Nc + n] = p;
}

// s[b,m,n] = sum_d Ym[b,m,d]*Xn[b,n,d]; grid (Nc, BM)
__global__ __launch_bounds__(256) void bilin_scores(const float* __restrict__ Ym,
                                                    const float* __restrict__ Xn,
                                                    float* __restrict__ S) {
  const int n = blockIdx.x;
  const int bm = blockIdx.y;
  const int b = bm >> 7;
  const float* yrow = Ym + (size_t)bm * Dc;
  const float* xrow = Xn + (size_t)(b * Nc + n) * Dc;
  const int tid = threadIdx.x;
  float p = 0.f;
  #pragma unroll
  for (int d = tid; d < Dc; d += 256) p = fmaf(yrow[d], xrow[d], p);
  __shared__ float buf4[4];
  p = block_sum256(p, buf4);
  if (tid == 0) S[(size_t)bm * Nc + n] = p;
}

// in-place softmax over last dim (=128); one row per block, 128 threads
__global__ __launch_bounds__(128) void softmax128(float* __restrict__ S) {
  const int row = blockIdx.x;
  const int tid = threadIdx.x;
  float x = S[(size_t)row * 128 + tid];
  __shared__ float mbuf[2], sbuf[2];
  float mx = x;
  #pragma unroll
  for (int o = 32; o; o >>= 1) mx = fmaxf(mx, __shfl_down(mx, o, 64));
  if ((tid & 63) == 0) mbuf[tid >> 6] = mx;
  __syncthreads();
  mx = fmaxf(mbuf[0], mbuf[1]);
  float e = __expf(x - mx);
  float sm = e;
  #pragma unroll
  for (int o = 32; o; o >>= 1) sm += __shfl_down(sm, o, 64);
  if ((tid & 63) == 0) sbuf[tid >> 6] = sm;
  __syncthreads();
  sm = sbuf[0] + sbuf[1];
  S[(size_t)row * 128 + tid] = e / sm;
}

#define FMA4(acc, s, v)                  \
  acc.x = fmaf(s, v.x, acc.x);           \
  acc.y = fmaf(s, v.y, acc.y);           \
  acc.z = fmaf(s, v.z, acc.z);           \
  acc.w = fmaf(s, v.w, acc.w)

// agg[b,m,d] = max(x1[b,m,d], qtc, qtb, qts, qtd, qtm); grid (BM), 256 threads x 4 d each
__global__ __launch_bounds__(256) void agg_max(const float* __restrict__ x0,
                                               const float* __restrict__ x1,
                                               const float* __restrict__ Sc,
                                               const float* __restrict__ Sb,
                                               const float* __restrict__ Sd1,
                                               const float* __restrict__ Sd2,
                                               const float* __restrict__ Sm,
                                               float* __restrict__ agg) {
  const int bm = blockIdx.x;
  const int b = bm >> 7;
  const int tid = threadIdx.x;
  __shared__ float w[5][128];
  if (tid < 128) {
    w[0][tid] = Sc[(size_t)bm * Nc + tid];
    w[1][tid] = Sb[(size_t)bm * Nc + tid];
    w[2][tid] = Sd1[(size_t)bm * Nc + tid];
    w[3][tid] = Sd2[(size_t)bm * Nc + tid];
    w[4][tid] = Sm[(size_t)bm * Nc + tid];
  }
  __syncthreads();
  const int d0 = tid * 4;
  float4 qc = {0, 0, 0, 0}, qb = {0, 0, 0, 0}, qs = {0, 0, 0, 0};
  float4 qd = {0, 0, 0, 0}, qm = {0, 0, 0, 0};
  const float* X0b = x0 + (size_t)b * Nc * Dc;
  const float* X1b = x1 + (size_t)b * Nc * Dc;
  for (int n = 0; n < Nc; n++) {
    float4 xv = *reinterpret_cast<const float4*>(&X0b[(size_t)n * Dc + d0]);
    float4 yv = *reinterpret_cast<const float4*>(&X1b[(size_t)n * Dc + d0]);
    float wc = w[0][n], wb = w[1][n], ws = w[2][n], wd = w[3][n], wm = w[4][n];
    FMA4(qc, wc, xv);  // concat att -> x0
    FMA4(qb, wb, xv);  // bilinear -> x0
    FMA4(qs, ws, xv);  // dot1 (x=x0) -> x0
    FMA4(qd, wd, yv);  // dot2 (x=x1) -> x1
    FMA4(qm, wm, xv);  // minus -> x0
  }
  float4 x1v = *reinterpret_cast<const float4*>(&x1[(size_t)bm * Dc + d0]);
  float4 r;
  r.x = fmaxf(x1v.x, fmaxf(fmaxf(qs.x, qc.x), fmaxf(fmaxf(qd.x, qb.x), qm.x)));
  r.y = fmaxf(x1v.y, fmaxf(fmaxf(qs.y, qc.y), fmaxf(fmaxf(qd.y, qb.y), qm.y)));
  r.z = fmaxf(x1v.z, fmaxf(fmaxf(qs.z, qc.z), fmaxf(fmaxf(qd.z, qb.z), qm.z)));
  r.w = fmaxf(x1v.w, fmaxf(fmaxf(qs.w, qc.w), fmaxf(fmaxf(qd.w, qb.w), qm.w)));
  *reinterpret_cast<float4*>(&agg[(size_t)bm * Dc + d0]) = r;
}

// u[d2] = sum_h Wp1[d2,h]*vp[h]; grid (2*Dc), 64 threads
__global__ __launch_bounds__(64) void compute_u(const float* __restrict__ Wp1,
                                                const float* __restrict__ vp,
                                                float* __restrict__ u) {
  const int d2 = blockIdx.x;
  const int tid = threadIdx.x;
  float p = 0.f;
  #pragma unroll
  for (int h = tid; h < Hc; h += 64) p = fmaf(Wp1[(size_t)d2 * Hc + h], vp[h], p);
  #pragma unroll
  for (int o = 32; o; o >>= 1) p += __shfl_down(p, o, 64);
  if (tid == 0) u[d2] = p;
}

// score[bm] = x1[bm,:].u[0:D] + agg[bm,:].u[D:2D]   (rq@Wp2 term is softmax-invariant)
__global__ __launch_bounds__(256) void final_scores(const float* __restrict__ x1,
                                                    const float* __restrict__ agg,
                                                    const float* __restrict__ u,
                                                    float* __restrict__ score) {
  const int bm = blockIdx.x;
  const int tid = threadIdx.x;
  float p = 0.f;
  #pragma unroll
  for (int d = tid; d < Dc; d += 256)
    p = fmaf(x1[(size_t)bm * Dc + d], u[d], fmaf(agg[(size_t)bm * Dc + d], u[Dc + d], p));
  __shared__ float buf4[4];
  p = block_sum256(p, buf4);
  if (tid == 0) score[bm] = p;
}

// out[b,j] = relu( sum_m sp[b,m]*(cat[b,m,:].Wpred[:,j]) + bpred[j] ); grid (B), 256 thr
__global__ __launch_bounds__(256) void final_out(const float* __restrict__ x1,
                                                 const float* __restrict__ agg,
                                                 const float* __restrict__ sp,
                                                 const float* __restrict__ Wpred,
                                                 const float* __restrict__ bpred,
                                                 float* __restrict__ out) {
  const int b = blockIdx.x;
  const int tid = threadIdx.x;
  __shared__ float spL[128];
  if (tid < 128) spL[tid] = sp[b * Nc + tid];
  __syncthreads();
  const int d2 = tid * 8;  // 256*8 = 2048, chunks never straddle the x1/agg boundary
  float w0[8], w1[8];
  #pragma unroll
  for (int i = 0; i < 8; i++) {
    w0[i] = Wpred[(size_t)(d2 + i) * 2 + 0];
    w1[i] = Wpred[(size_t)(d2 + i) * 2 + 1];
  }
  const float* src = (d2 < Dc) ? (x1 + (size_t)b * Nc * Dc + d2)
                               : (agg + (size_t)b * Nc * Dc + (d2 - Dc));
  float p0 = 0.f, p1 = 0.f;
  for (int m = 0; m < Nc; m++) {
    float s = spL[m];
    const float* r = src + (size_t)m * Dc;
    #pragma unroll
    for (int i = 0; i < 8; i++) {
      float sc = s * r[i];
      p0 = fmaf(sc, w0[i], p0);
      p1 = fmaf(sc, w1[i], p1);
    }
  }
  #pragma unroll
  for (int o = 32; o; o >>= 1) {
    p0 += __shfl_down(p0, o, 64);
    p1 += __shfl_down(p1, o, 64);
  }
  __shared__ float r0[4], r1[4];
  const int w = tid >> 6, lane = tid & 63;
  if (lane == 0) { r0[w] = p0; r1[w] = p1; }
  __syncthreads();
  if (tid == 0) {
    float q0 = r0[0] + r0[1] + r0[2] + r0[3] + bpred[0];
    float q1 = r1[0] + r1[1] + r1[2] + r1[3] + bpred[1];
    out[b * 2 + 0] = fmaxf(q0, 0.f);
    out[b * 2 + 1] = fmaxf(q1, 0.f);
  }
}

extern "C" void kernel_launch(void* const* d_in, const int* in_sizes, int n_in,
                              void* d_out, int out_size, void* d_ws, size_t ws_size,
                              hipStream_t stream) {
  const float* x0    = (const float*)d_in[0];
  const float* x1    = (const float*)d_in[1];
  const float* Wc1   = (const float*)d_in[2];
  const float* Wc2   = (const float*)d_in[3];
  const float* vc    = (const float*)d_in[4];
  const float* Wb    = (const float*)d_in[5];
  const float* Wd1   = (const float*)d_in[6];
  const float* vd1   = (const float*)d_in[7];
  const float* Wd2   = (const float*)d_in[8];
  const float* vd2   = (const float*)d_in[9];
  const float* Wm    = (const float*)d_in[10];
  const float* vm    = (const float*)d_in[11];
  // d_in[12]=Wq, d_in[13]=vq, d_in[15]=Wp2: provably dead (softmax shift-invariance)
  const float* Wp1   = (const float*)d_in[14];
  const float* vp    = (const float*)d_in[16];
  const float* Wpred = (const float*)d_in[17];
  const float* bpred = (const float*)d_in[18];
  float* out = (float*)d_out;

  float* ws = (float*)d_ws;
  float* ac     = ws;               // [B,N,H]  524288
  float* bcv    = ac + 524288;      // [B,N,H]
  float* am     = bcv + 524288;     // [B,N,H]
  float* bmv    = am + 524288;      // [B,N,H]
  float* xWb    = bmv + 524288;     // [B,N,D] 1048576
  float* sc     = xWb + 1048576;    // 5 contiguous score tensors [B,M,N] = 131072 each
  float* sb     = sc + 131072;
  float* sd1    = sb + 131072;
  float* sd2    = sd1 + 131072;
  float* smv    = sd2 + 131072;
  float* agg    = smv + 131072;     // [B,M,D] 1048576
  float* u      = agg + 1048576;    // [2D] 2048
  float* score2 = u + 2048;         // [B*M] 1024
  ushort* wdT1  = (ushort*)(score2 + 1024);   // [H,D] bf16, 524288 ushorts
  ushort* wdT2  = wdT1 + 524288;              // [H,D] bf16
  // total ~21.5 MB

  // --- weight prep for MFMA path ---
  conv_transpose_w<<<dim3(Dc / 64, Hc / 64), 256, 0, stream>>>(Wd1, wdT1);
  conv_transpose_w<<<dim3(Dc / 64, Hc / 64), 256, 0, stream>>>(Wd2, wdT2);

  // --- projections ---
  gemm_rm<<<dim3(Hc / 64, BM / 64), 256, 0, stream>>>(x0, Wc1, ac, Dc, Hc);
  gemm_rm<<<dim3(Hc / 64, BM / 64), 256, 0, stream>>>(x1, Wc2, bcv, Dc, Hc);
  gemm_rm<<<dim3(Hc / 64, BM / 64), 256, 0, stream>>>(x0, Wm, am, Dc, Hc);
  gemm_rm<<<dim3(Hc / 64, BM / 64), 256, 0, stream>>>(x1, Wm, bmv, Dc, Hc);
  gemm_rm<<<dim3(Dc / 64, BM / 64), 256, 0, stream>>>(x0, Wb, xWb, Dc, Dc);

  // --- attention scores ---
  addtanh_scores<<<dim3(Nc, BM), 256, 0, stream>>>(ac, bcv, vc, 1.f, sc);
  addtanh_scores<<<dim3(Nc, BM), 256, 0, stream>>>(am, bmv, vm, -1.f, smv);
  bilin_scores<<<dim3(Nc, BM), 256, 0, stream>>>(x1, xWb, sb);
  (void)hipMemsetAsync(sd1, 0, 2 * 131072 * sizeof(float), stream);  // sd1+sd2 contiguous
  dot_scores_mfma2<<<dim3(2, BM), 256, 0, stream>>>(x0, x1, wdT1, vd1, sd1);
  dot_scores_mfma2<<<dim3(2, BM), 256, 0, stream>>>(x1, x0, wdT2, vd2, sd2);

  // --- softmax over n for all 5 score tensors (contiguous rows) ---
  softmax128<<<5 * BM, 128, 0, stream>>>(sc);

  // --- weighted sums + elementwise max ---
  agg_max<<<BM, 256, 0, stream>>>(x0, x1, sc, sb, sd1, sd2, smv, agg);

  // --- aggregation (rq path dropped: softmax shift-invariant; Wp1@vp prefolded) ---
  compute_u<<<2 * Dc, 64, 0, stream>>>(Wp1, vp, u);
  final_scores<<<BM, 256, 0, stream>>>(x1, agg, u, score2);
  softmax128<<<Bc, 128, 0, stream>>>(score2);
  final_out<<<Bc, 256, 0, stream>>>(x1, agg, score2, Wpred, bpred, out);
}

// Round 5
// 1033.278 us; speedup vs baseline: 5.0615x; 1.1317x over previous
//
#include <hip/hip_runtime.h>
#include <hip/hip_bf16.h>

// Shapes (fixed by the reference): B=8, N=M=128, D=1024, H=512
static constexpr int Bc = 8, Nc = 128, Dc = 1024, Hc = 512;
static constexpr int BM = Bc * Nc;  // 1024

typedef short short8 __attribute__((ext_vector_type(8)));
typedef float floatx4 __attribute__((ext_vector_type(4)));

__device__ __forceinline__ float fast_tanh(float x) {
  x = fminf(fmaxf(x, -15.f), 15.f);
  float e = __expf(2.f * x);
  return (e - 1.f) / (e + 1.f);
}

__device__ __forceinline__ ushort f2bf(float f) {  // round-to-nearest-even
  unsigned u = __float_as_uint(f);
  u += 0x7FFFu + ((u >> 16) & 1u);
  return (ushort)(u >> 16);
}

__device__ __forceinline__ unsigned pk2(float a, float b) {  // packed bf16 pair (RNE)
  return (unsigned)f2bf(a) | ((unsigned)f2bf(b) << 16);
}

// sum over 256-thread block; result broadcast to all threads
__device__ __forceinline__ float block_sum256(float v, float* buf4) {
  #pragma unroll
  for (int o = 32; o; o >>= 1) v += __shfl_down(v, o, 64);
  const int w = threadIdx.x >> 6, lane = threadIdx.x & 63;
  if (lane == 0) buf4[w] = v;
  __syncthreads();
  return buf4[0] + buf4[1] + buf4[2] + buf4[3];
}

// fp32 -> bf16 elementwise, n multiple of 2048, grid n/2048
__global__ __launch_bounds__(256) void cvt_bf16x(const float* __restrict__ src,
                                                 ushort* __restrict__ dst, int n) {
  int i = (blockIdx.x * 256 + threadIdx.x) * 8;
  if (i >= n) return;
  float4 a = *reinterpret_cast<const float4*>(&src[i]);
  float4 b = *reinterpret_cast<const float4*>(&src[i + 4]);
  uint4 o;
  o.x = pk2(a.x, a.y); o.y = pk2(a.z, a.w);
  o.z = pk2(b.x, b.y); o.w = pk2(b.z, b.w);
  *reinterpret_cast<uint4*>(&dst[i]) = o;
}

// Transpose + convert W [Dc, J] fp32 -> WT [J, Dc] bf16. grid (Dc/64, J/64), 256 thr.
__global__ __launch_bounds__(256) void conv_transpose_w(const float* __restrict__ W,
                                                        ushort* __restrict__ WT, int J) {
  __shared__ float tile[64][65];  // 65: conflict-free column reads
  const int d0 = blockIdx.x * 64;
  const int h0 = blockIdx.y * 64;
  const int tid = threadIdx.x;
  #pragma unroll
  for (int i = 0; i < 16; i++) {
    int idx = tid + i * 256;
    int dd = idx >> 6, hh = idx & 63;
    tile[dd][hh] = W[(size_t)(d0 + dd) * J + h0 + hh];
  }
  __syncthreads();
  #pragma unroll
  for (int i = 0; i < 16; i++) {
    int idx = tid + i * 256;
    int hh = idx >> 6, dd = idx & 63;
    WT[(size_t)(h0 + hh) * Dc + d0 + dd] = f2bf(tile[dd][hh]);
  }
}

// C[m,n] = sum_k A[m,k]*BT[n,k]; bf16 in, fp32 or bf16 out (exactly one of Cf/Cbf).
// A [.,K] lda=K, BT [.,K] ldb=K. grid (N/64, M/64, batch), 256 thr, 64x64 tile.
__global__ __launch_bounds__(256) void gemm_bt(const ushort* __restrict__ A,
                                               const ushort* __restrict__ BT,
                                               float* __restrict__ Cf,
                                               ushort* __restrict__ Cbf,
                                               int K, int ldc,
                                               size_t sA, size_t sB, size_t sC) {
  const int bz = blockIdx.z;
  A  += (size_t)bz * sA;
  BT += (size_t)bz * sB;
  const int m0 = blockIdx.y * 64, n0 = blockIdx.x * 64;
  __shared__ __align__(16) ushort Asl[64][40];
  __shared__ __align__(16) ushort Bsl[64][40];
  const int tid = threadIdx.x, wave = tid >> 6, lane = tid & 63;
  const int quad = lane >> 4, l15 = lane & 15;
  const int wr = (wave & 1) * 32, wc = (wave >> 1) * 32;
  const int rSt = tid >> 2, kSt8 = (tid & 3) * 8;
  floatx4 acc[2][2];
  #pragma unroll
  for (int i = 0; i < 2; i++)
    #pragma unroll
    for (int j = 0; j < 2; j++) acc[i][j] = (floatx4){0.f, 0.f, 0.f, 0.f};
  // prefetch slab 0
  uint4 pa = *reinterpret_cast<const uint4*>(&A[(size_t)(m0 + rSt) * K + kSt8]);
  uint4 pb = *reinterpret_cast<const uint4*>(&BT[(size_t)(n0 + rSt) * K + kSt8]);
  for (int k0 = 0; k0 < K; k0 += 32) {
    *reinterpret_cast<uint4*>(&Asl[rSt][kSt8]) = pa;
    *reinterpret_cast<uint4*>(&Bsl[rSt][kSt8]) = pb;
    __syncthreads();
    if (k0 + 32 < K) {
      pa = *reinterpret_cast<const uint4*>(&A[(size_t)(m0 + rSt) * K + k0 + 32 + kSt8]);
      pb = *reinterpret_cast<const uint4*>(&BT[(size_t)(n0 + rSt) * K + k0 + 32 + kSt8]);
    }
    short8 af[2], bb[2];
    #pragma unroll
    for (int i = 0; i < 2; i++)
      af[i] = *reinterpret_cast<const short8*>(&Asl[wr + i * 16 + l15][quad * 8]);
    #pragma unroll
    for (int j = 0; j < 2; j++)
      bb[j] = *reinterpret_cast<const short8*>(&Bsl[wc + j * 16 + l15][quad * 8]);
    #pragma unroll
    for (int i = 0; i < 2; i++)
      #pragma unroll
      for (int j = 0; j < 2; j++)
        acc[i][j] = __builtin_amdgcn_mfma_f32_16x16x32_bf16(af[i], bb[j], acc[i][j], 0, 0, 0);
    __syncthreads();
  }
  // C/D layout (verified R2/R4): row = quad*4 + reg, col = l15 within each 16x16 frag
  if (Cbf) {
    #pragma unroll
    for (int i = 0; i < 2; i++)
      #pragma unroll
      for (int j = 0; j < 2; j++)
        #pragma unroll
        for (int r = 0; r < 4; r++) {
          int row = m0 + wr + i * 16 + quad * 4 + r;
          int col = n0 + wc + j * 16 + l15;
          Cbf[(size_t)bz * sC + (size_t)row * ldc + col] = f2bf(acc[i][j][r]);
        }
  } else {
    #pragma unroll
    for (int i = 0; i < 2; i++)
      #pragma unroll
      for (int j = 0; j < 2; j++)
        #pragma unroll
        for (int r = 0; r < 4; r++) {
          int row = m0 + wr + i * 16 + quad * 4 + r;
          int col = n0 + wc + j * 16 + l15;
          Cf[(size_t)bz * sC + (size_t)row * ldc + col] = acc[i][j][r];
        }
  }
}

// s[b,m,n] += sum_h v[h]*tanh( sum_d X[b,n,d]*Y[b,m,d]*Wd[d,h] )  via bf16 MFMA.
// Block: one (b,m), ALL 128 n, one 256-wide h half, K=1024. grid (2, BM).
// 4 waves in 2x2: each wave owns a 64n x 128h tile = 4x8 16x16x32 frags (128 AGPR).
// Register prefetch of next slab's global loads overlaps MFMA with load latency.
__global__ __launch_bounds__(256, 2) void dot_scores_mfma2(const float* __restrict__ X,
                                                           const float* __restrict__ Y,
                                                           const ushort* __restrict__ WdT,
                                                           const float* __restrict__ v,
                                                           float* __restrict__ S) {
  const int bm = blockIdx.y;
  const int b = bm >> 7;
  const int hBase = blockIdx.x * 256;
  const int tid = threadIdx.x;
  const int wave = tid >> 6, lane = tid & 63;
  const int quad = lane >> 4, l15 = lane & 15;
  const int wn = wave & 1, wh = wave >> 1;

  __shared__ __align__(16) ushort As[128][40];   // 10.0 KB
  __shared__ __align__(16) ushort Bs[256][40];   // 20.0 KB
  __shared__ __align__(16) float yl[Dc];         //  4.0 KB
  __shared__ float red[128][33];                 // 16.9 KB

  for (int i = tid; i < Dc; i += 256) yl[i] = Y[(size_t)bm * Dc + i];

  floatx4 acc[4][8];
  #pragma unroll
  for (int i = 0; i < 4; i++)
    #pragma unroll
    for (int j = 0; j < 8; j++) acc[i][j] = (floatx4){0.f, 0.f, 0.f, 0.f};

  const float* Xb = X + (size_t)b * Nc * Dc;
  const int nSt = tid >> 2;
  const int kSt4 = (tid & 3) * 4;
  const int kSt8 = (tid & 3) * 8;

  // prefetch slab 0 globals
  float4 ax[4];
  uint4 bx[4];
  #pragma unroll
  for (int u = 0; u < 4; u++) {
    const int n = (u >> 1) * 64 + nSt;
    const int kc = (u & 1) * 16 + kSt4;
    ax[u] = *reinterpret_cast<const float4*>(&Xb[(size_t)n * Dc + kc]);
  }
  #pragma unroll
  for (int r = 0; r < 4; r++)
    bx[r] = *reinterpret_cast<const uint4*>(&WdT[(size_t)(hBase + r * 64 + nSt) * Dc + kSt8]);

  __syncthreads();  // yl ready

  for (int k0 = 0; k0 < Dc; k0 += 32) {
    // stage A (convert via yl) and B from prefetched regs
    #pragma unroll
    for (int u = 0; u < 4; u++) {
      const int n = (u >> 1) * 64 + nSt;
      const int kc = (u & 1) * 16 + kSt4;
      float4 yv = *reinterpret_cast<const float4*>(&yl[k0 + kc]);
      uint2 o;
      o.x = pk2(ax[u].x * yv.x, ax[u].y * yv.y);
      o.y = pk2(ax[u].z * yv.z, ax[u].w * yv.w);
      *reinterpret_cast<uint2*>(&As[n][kc]) = o;
    }
    #pragma unroll
    for (int r = 0; r < 4; r++)
      *reinterpret_cast<uint4*>(&Bs[r * 64 + nSt][kSt8]) = bx[r];
    __syncthreads();
    // prefetch next slab while MFMA runs
    if (k0 + 32 < Dc) {
      #pragma unroll
      for (int u = 0; u < 4; u++) {
        const int n = (u >> 1) * 64 + nSt;
        const int kc = (u & 1) * 16 + kSt4;
        ax[u] = *reinterpret_cast<const float4*>(&Xb[(size_t)n * Dc + k0 + 32 + kc]);
      }
      #pragma unroll
      for (int r = 0; r < 4; r++)
        bx[r] = *reinterpret_cast<const uint4*>(
            &WdT[(size_t)(hBase + r * 64 + nSt) * Dc + k0 + 32 + kSt8]);
    }
    short8 af[4], bf[8];
    #pragma unroll
    for (int i = 0; i < 4; i++)
      af[i] = *reinterpret_cast<const short8*>(&As[wn * 64 + i * 16 + l15][quad * 8]);
    #pragma unroll
    for (int j = 0; j < 8; j++)
      bf[j] = *reinterpret_cast<const short8*>(&Bs[wh * 128 + j * 16 + l15][quad * 8]);
    #pragma unroll
    for (int i = 0; i < 4; i++)
      #pragma unroll
      for (int j = 0; j < 8; j++)
        acc[i][j] = __builtin_amdgcn_mfma_f32_16x16x32_bf16(af[i], bf[j], acc[i][j], 0, 0, 0);
    __syncthreads();
  }

  // epilogue: p[n] = sum over this wave's 128 h of v[h]*tanh(z[n,h])
  float vv[8];
  #pragma unroll
  for (int j = 0; j < 8; j++) vv[j] = v[hBase + wh * 128 + j * 16 + l15];
  #pragma unroll
  for (int i = 0; i < 4; i++)
    #pragma unroll
    for (int r = 0; r < 4; r++) {
      float p = 0.f;
      #pragma unroll
      for (int j = 0; j < 8; j++) p = fmaf(vv[j], fast_tanh(acc[i][j][r]), p);
      red[wn * 64 + i * 16 + quad * 4 + r][wh * 16 + l15] = p;
    }
  __syncthreads();
  if (tid < 128) {
    float s = 0.f;
    #pragma unroll
    for (int c = 0; c < 32; c++) s += red[tid][c];
    atomicAdd(&S[(size_t)bm * Nc + tid], s);
  }
}

// s[b,m,n] = sum_h v[h]*tanh(Arow[b,n,:] + sign*Brow[b,m,:]) tiled 16m x 16n x 512h.
// grid (8 nt, 8 mt, B), 256 thr. Arow/Brow are projection bases (row stride = rs).
__global__ __launch_bounds__(256) void addtanh_tiled(const float* __restrict__ Arow,
                                                     const float* __restrict__ Brow,
                                                     const float* __restrict__ v,
                                                     float sign, float* __restrict__ S,
                                                     int rs) {
  const int nt = blockIdx.x, mt = blockIdx.y, b = blockIdx.z;
  __shared__ __align__(16) float at[16][516];   // 516: float4-aligned, 2-way-max banks
  __shared__ __align__(16) float bt2[16][516];
  __shared__ __align__(16) float vl[512];
  const int tid = threadIdx.x;
  #pragma unroll
  for (int p = 0; p < 8; p++) {
    int idx = p * 256 + tid;        // 0..2047: 16 rows x 128 float4
    int r = idx >> 7, c4 = (idx & 127) * 4;
    *reinterpret_cast<float4*>(&at[r][c4]) =
        *reinterpret_cast<const float4*>(&Arow[(size_t)(b * Nc + nt * 16 + r) * rs + c4]);
    *reinterpret_cast<float4*>(&bt2[r][c4]) =
        *reinterpret_cast<const float4*>(&Brow[(size_t)(b * Nc + mt * 16 + r) * rs + c4]);
  }
  if (tid < 128)
    *reinterpret_cast<float4*>(&vl[tid * 4]) = *reinterpret_cast<const float4*>(&v[tid * 4]);
  __syncthreads();
  const int m = tid >> 4, n = tid & 15;
  float acc = 0.f;
  #pragma unroll 4
  for (int c = 0; c < 512; c += 4) {
    float4 av = *reinterpret_cast<const float4*>(&at[n][c]);
    float4 bv = *reinterpret_cast<const float4*>(&bt2[m][c]);
    float4 vv = *reinterpret_cast<const float4*>(&vl[c]);
    acc = fmaf(vv.x, fast_tanh(fmaf(sign, bv.x, av.x)), acc);
    acc = fmaf(vv.y, fast_tanh(fmaf(sign, bv.y, av.y)), acc);
    acc = fmaf(vv.z, fast_tanh(fmaf(sign, bv.z, av.z)), acc);
    acc = fmaf(vv.w, fast_tanh(fmaf(sign, bv.w, av.w)), acc);
  }
  S[(size_t)(b * Nc + mt * 16 + m) * Nc + nt * 16 + n] = acc;
}

// in-place softmax over last dim (=128); one row per block, 128 threads
__global__ __launch_bounds__(128) void softmax128(float* __restrict__ S) {
  const int row = blockIdx.x;
  const int tid = threadIdx.x;
  float x = S[(size_t)row * 128 + tid];
  __shared__ float mbuf[2], sbuf[2];
  float mx = x;
  #pragma unroll
  for (int o = 32; o; o >>= 1) mx = fmaxf(mx, __shfl_down(mx, o, 64));
  if ((tid & 63) == 0) mbuf[tid >> 6] = mx;
  __syncthreads();
  mx = fmaxf(mbuf[0], mbuf[1]);
  float e = __expf(x - mx);
  float sm = e;
  #pragma unroll
  for (int o = 32; o; o >>= 1) sm += __shfl_down(sm, o, 64);
  if ((tid & 63) == 0) sbuf[tid >> 6] = sm;
  __syncthreads();
  sm = sbuf[0] + sbuf[1];
  S[(size_t)row * 128 + tid] = e / sm;
}

#define FMA4(acc, s, v)                  \
  acc.x = fmaf(s, v.x, acc.x);           \
  acc.y = fmaf(s, v.y, acc.y);           \
  acc.z = fmaf(s, v.z, acc.z);           \
  acc.w = fmaf(s, v.w, acc.w)

// agg[b,m,d] = max(x1[b,m,d], qtc, qtb, qts, qtd, qtm); grid (BM), 256 threads x 4 d each
__global__ __launch_bounds__(256) void agg_max(const float* __restrict__ x0,
                                               const float* __restrict__ x1,
                                               const float* __restrict__ Sc,
                                               const float* __restrict__ Sb,
                                               const float* __restrict__ Sd1,
                                               const float* __restrict__ Sd2,
                                               const float* __restrict__ Sm,
                                               float* __restrict__ agg) {
  const int bm = blockIdx.x;
  const int b = bm >> 7;
  const int tid = threadIdx.x;
  __shared__ float w[5][128];
  if (tid < 128) {
    w[0][tid] = Sc[(size_t)bm * Nc + tid];
    w[1][tid] = Sb[(size_t)bm * Nc + tid];
    w[2][tid] = Sd1[(size_t)bm * Nc + tid];
    w[3][tid] = Sd2[(size_t)bm * Nc + tid];
    w[4][tid] = Sm[(size_t)bm * Nc + tid];
  }
  __syncthreads();
  const int d0 = tid * 4;
  float4 qc = {0, 0, 0, 0}, qb = {0, 0, 0, 0}, qs = {0, 0, 0, 0};
  float4 qd = {0, 0, 0, 0}, qm = {0, 0, 0, 0};
  const float* X0b = x0 + (size_t)b * Nc * Dc;
  const float* X1b = x1 + (size_t)b * Nc * Dc;
  for (int n = 0; n < Nc; n++) {
    float4 xv = *reinterpret_cast<const float4*>(&X0b[(size_t)n * Dc + d0]);
    float4 yv = *reinterpret_cast<const float4*>(&X1b[(size_t)n * Dc + d0]);
    float wc = w[0][n], wb = w[1][n], ws = w[2][n], wd = w[3][n], wm = w[4][n];
    FMA4(qc, wc, xv);
    FMA4(qb, wb, xv);
    FMA4(qs, ws, xv);
    FMA4(qd, wd, yv);
    FMA4(qm, wm, xv);
  }
  float4 x1v = *reinterpret_cast<const float4*>(&x1[(size_t)bm * Dc + d0]);
  float4 r;
  r.x = fmaxf(x1v.x, fmaxf(fmaxf(qs.x, qc.x), fmaxf(fmaxf(qd.x, qb.x), qm.x)));
  r.y = fmaxf(x1v.y, fmaxf(fmaxf(qs.y, qc.y), fmaxf(fmaxf(qd.y, qb.y), qm.y)));
  r.z = fmaxf(x1v.z, fmaxf(fmaxf(qs.z, qc.z), fmaxf(fmaxf(qd.z, qb.z), qm.z)));
  r.w = fmaxf(x1v.w, fmaxf(fmaxf(qs.w, qc.w), fmaxf(fmaxf(qd.w, qb.w), qm.w)));
  *reinterpret_cast<float4*>(&agg[(size_t)bm * Dc + d0]) = r;
}

// u[d2] = sum_h Wp1[d2,h]*vp[h]; grid (2*Dc), 64 threads
__global__ __launch_bounds__(64) void compute_u(const float* __restrict__ Wp1,
                                                const float* __restrict__ vp,
                                                float* __restrict__ u) {
  const int d2 = blockIdx.x;
  const int tid = threadIdx.x;
  float p = 0.f;
  #pragma unroll
  for (int h = tid; h < Hc; h += 64) p = fmaf(Wp1[(size_t)d2 * Hc + h], vp[h], p);
  #pragma unroll
  for (int o = 32; o; o >>= 1) p += __shfl_down(p, o, 64);
  if (tid == 0) u[d2] = p;
}

// score[bm] = x1[bm,:].u[0:D] + agg[bm,:].u[D:2D]   (rq@Wp2 term is softmax-invariant)
__global__ __launch_bounds__(256) void final_scores(const float* __restrict__ x1,
                                                    const float* __restrict__ agg,
                                                    const float* __restrict__ u,
                                                    float* __restrict__ score) {
  const int bm = blockIdx.x;
  const int tid = threadIdx.x;
  float p = 0.f;
  #pragma unroll
  for (int d = tid; d < Dc; d += 256)
    p = fmaf(x1[(size_t)bm * Dc + d], u[d], fmaf(agg[(size_t)bm * Dc + d], u[Dc + d], p));
  __shared__ float buf4[4];
  p = block_sum256(p, buf4);
  if (tid == 0) score[bm] = p;
}

// out[b,j] = relu( sum_m sp[b,m]*(cat[b,m,:].Wpred[:,j]) + bpred[j] ); grid (B), 256 thr
__global__ __launch_bounds__(256) void final_out(const float* __restrict__ x1,
                                                 const float* __restrict__ agg,
                                                 const float* __restrict__ sp,
                                                 const float* __restrict__ Wpred,
                                                 const float* __restrict__ bpred,
                                                 float* __restrict__ out) {
  const int b = blockIdx.x;
  const int tid = threadIdx.x;
  __shared__ float spL[128];
  if (tid < 128) spL[tid] = sp[b * Nc + tid];
  __syncthreads();
  const int d2 = tid * 8;
  float w0[8], w1[8];
  #pragma unroll
  for (int i = 0; i < 8; i++) {
    w0[i] = Wpred[(size_t)(d2 + i) * 2 + 0];
    w1[i] = Wpred[(size_t)(d2 + i) * 2 + 1];
  }
  const float* src = (d2 < Dc) ? (x1 + (size_t)b * Nc * Dc + d2)
                               : (agg + (size_t)b * Nc * Dc + (d2 - Dc));
  float p0 = 0.f, p1 = 0.f;
  for (int m = 0; m < Nc; m++) {
    float s = spL[m];
    const float* r = src + (size_t)m * Dc;
    #pragma unroll
    for (int i = 0; i < 8; i++) {
      float sc = s * r[i];
      p0 = fmaf(sc, w0[i], p0);
      p1 = fmaf(sc, w1[i], p1);
    }
  }
  #pragma unroll
  for (int o = 32; o; o >>= 1) {
    p0 += __shfl_down(p0, o, 64);
    p1 += __shfl_down(p1, o, 64);
  }
  __shared__ float r0[4], r1[4];
  const int w = tid >> 6, lane = tid & 63;
  if (lane == 0) { r0[w] = p0; r1[w] = p1; }
  __syncthreads();
  if (tid == 0) {
    float q0 = r0[0] + r0[1] + r0[2] + r0[3] + bpred[0];
    float q1 = r1[0] + r1[1] + r1[2] + r1[3] + bpred[1];
    out[b * 2 + 0] = fmaxf(q0, 0.f);
    out[b * 2 + 1] = fmaxf(q1, 0.f);
  }
}

extern "C" void kernel_launch(void* const* d_in, const int* in_sizes, int n_in,
                              void* d_out, int out_size, void* d_ws, size_t ws_size,
                              hipStream_t stream) {
  const float* x0    = (const float*)d_in[0];
  const float* x1    = (const float*)d_in[1];
  const float* Wc1   = (const float*)d_in[2];
  const float* Wc2   = (const float*)d_in[3];
  const float* vc    = (const float*)d_in[4];
  const float* Wb    = (const float*)d_in[5];
  const float* Wd1   = (const float*)d_in[6];
  const float* vd1   = (const float*)d_in[7];
  const float* Wd2   = (const float*)d_in[8];
  const float* vd2   = (const float*)d_in[9];
  const float* Wm    = (const float*)d_in[10];
  const float* vm    = (const float*)d_in[11];
  // d_in[12]=Wq, d_in[13]=vq, d_in[15]=Wp2: provably dead (softmax shift-invariance)
  const float* Wp1   = (const float*)d_in[14];
  const float* vp    = (const float*)d_in[16];
  const float* Wpred = (const float*)d_in[17];
  const float* bpred = (const float*)d_in[18];
  float* out = (float*)d_out;

  float* ws = (float*)d_ws;
  float* C1     = ws;               // [BM, 2H] fp32 (x0@[Wc1|Wm]); aliased as agg later
  float* C2     = C1 + 1048576;     // [BM, 2H] fp32 (x1@[Wc2|Wm])
  float* sc     = C2 + 1048576;     // 5 contiguous score tensors [B,M,N] = 131072 each
  float* sb     = sc + 131072;
  float* sd1    = sb + 131072;
  float* sd2    = sd1 + 131072;
  float* smv    = sd2 + 131072;
  float* u      = smv + 131072;     // [2D]
  float* score2 = u + 2048;         // [B*M]
  ushort* x0bf  = (ushort*)(score2 + 1024);   // [BM, D] bf16
  ushort* x1bf  = x0bf + 1048576;
  ushort* W1T   = x1bf + 1048576;   // [2H=1024, D] bf16: rows 0-511 Wc1^T, 512-1023 Wm^T
  ushort* W2T   = W1T + 1048576;    // rows 0-511 Wc2^T, 512-1023 Wm^T
  ushort* WbT   = W2T + 1048576;    // [D, D] bf16 (Wb^T)
  ushort* xWbbf = WbT + 1048576;    // [BM, D] bf16 (x0@Wb)
  ushort* wdT1  = xWbbf + 1048576;  // [H, D] bf16
  ushort* wdT2  = wdT1 + 524288;
  float* agg    = C1;               // alias: C1 dead after addtanh_tiled; agg written after
  // total ~25.7 MB

  // --- input/weight conversion ---
  cvt_bf16x<<<512, 256, 0, stream>>>(x0, x0bf, BM * Dc);
  cvt_bf16x<<<512, 256, 0, stream>>>(x1, x1bf, BM * Dc);
  conv_transpose_w<<<dim3(16, 8), 256, 0, stream>>>(Wd1, wdT1, Hc);
  conv_transpose_w<<<dim3(16, 8), 256, 0, stream>>>(Wd2, wdT2, Hc);
  conv_transpose_w<<<dim3(16, 8), 256, 0, stream>>>(Wc1, W1T, Hc);
  conv_transpose_w<<<dim3(16, 8), 256, 0, stream>>>(Wm, W1T + 512 * Dc, Hc);
  conv_transpose_w<<<dim3(16, 8), 256, 0, stream>>>(Wc2, W2T, Hc);
  conv_transpose_w<<<dim3(16, 8), 256, 0, stream>>>(Wm, W2T + 512 * Dc, Hc);
  conv_transpose_w<<<dim3(16, 16), 256, 0, stream>>>(Wb, WbT, Dc);

  // --- projections (bf16 MFMA) ---
  gemm_bt<<<dim3(16, 16, 1), 256, 0, stream>>>(x0bf, W1T, C1, nullptr, Dc, 1024, 0, 0, 0);
  gemm_bt<<<dim3(16, 16, 1), 256, 0, stream>>>(x1bf, W2T, C2, nullptr, Dc, 1024, 0, 0, 0);
  gemm_bt<<<dim3(16, 16, 1), 256, 0, stream>>>(x0bf, WbT, nullptr, xWbbf, Dc, 1024, 0, 0, 0);
  // bilinear scores: sb[b,m,n] = x1[b,m,:].xWb[b,n,:]
  gemm_bt<<<dim3(2, 2, 8), 256, 0, stream>>>(x1bf, xWbbf, sb, nullptr, Dc, 128,
                                             131072, 131072, 16384);

  // --- concat / minus scores (tiled tanh) ---
  addtanh_tiled<<<dim3(8, 8, 8), 256, 0, stream>>>(C1, C2, vc, 1.f, sc, 1024);
  addtanh_tiled<<<dim3(8, 8, 8), 256, 0, stream>>>(C1 + 512, C2 + 512, vm, -1.f, smv, 1024);

  // --- dot scores (bf16 MFMA, prefetched) ---
  (void)hipMemsetAsync(sd1, 0, 2 * 131072 * sizeof(float), stream);
  dot_scores_mfma2<<<dim3(2, BM), 256, 0, stream>>>(x0, x1, wdT1, vd1, sd1);
  dot_scores_mfma2<<<dim3(2, BM), 256, 0, stream>>>(x1, x0, wdT2, vd2, sd2);

  // --- softmax over n for all 5 score tensors (contiguous rows) ---
  softmax128<<<5 * BM, 128, 0, stream>>>(sc);

  // --- weighted sums + elementwise max (agg aliases C1) ---
  agg_max<<<BM, 256, 0, stream>>>(x0, x1, sc, sb, sd1, sd2, smv, agg);

  // --- aggregation (rq path dropped: softmax shift-invariant; Wp1@vp prefolded) ---
  compute_u<<<2 * Dc, 64, 0, stream>>>(Wp1, vp, u);
  final_scores<<<BM, 256, 0, stream>>>(x1, agg, u, score2);
  softmax128<<<Bc, 128, 0, stream>>>(score2);
  final_out<<<Bc, 256, 0, stream>>>(x1, agg, score2, Wpred, bpred, out);
}

// Round 6
// 701.087 us; speedup vs baseline: 7.4597x; 1.4738x over previous
//
#include <hip/hip_runtime.h>
#include <hip/hip_bf16.h>

// Shapes (fixed by the reference): B=8, N=M=128, D=1024, H=512
static constexpr int Bc = 8, Nc = 128, Dc = 1024, Hc = 512;
static constexpr int BM = Bc * Nc;  // 1024

typedef short short8 __attribute__((ext_vector_type(8)));
typedef float floatx4 __attribute__((ext_vector_type(4)));

__device__ __forceinline__ float fast_tanh(float x) {
  x = fminf(fmaxf(x, -15.f), 15.f);
  float e = __expf(2.f * x);
  return (e - 1.f) / (e + 1.f);
}

__device__ __forceinline__ ushort f2bf(float f) {  // round-to-nearest-even
  unsigned u = __float_as_uint(f);
  u += 0x7FFFu + ((u >> 16) & 1u);
  return (ushort)(u >> 16);
}

__device__ __forceinline__ unsigned pk2(float a, float b) {  // packed bf16 pair (RNE)
  return (unsigned)f2bf(a) | ((unsigned)f2bf(b) << 16);
}

// sum over 256-thread block; result broadcast to all threads
__device__ __forceinline__ float block_sum256(float v, float* buf4) {
  #pragma unroll
  for (int o = 32; o; o >>= 1) v += __shfl_down(v, o, 64);
  const int w = threadIdx.x >> 6, lane = threadIdx.x & 63;
  if (lane == 0) buf4[w] = v;
  __syncthreads();
  return buf4[0] + buf4[1] + buf4[2] + buf4[3];
}

// fp32 -> bf16 for x0 (blocks 0-511) and x1 (512-1023); each block converts 2048 elems
__global__ __launch_bounds__(256) void cvt_both(const float* __restrict__ x0,
                                                const float* __restrict__ x1,
                                                ushort* __restrict__ o0,
                                                ushort* __restrict__ o1) {
  int bi = blockIdx.x;
  const float* src = (bi < 512) ? x0 : x1;
  ushort* dst = (bi < 512) ? o0 : o1;
  int off = (bi & 511);
  int i = (off * 256 + threadIdx.x) * 8;
  float4 a = *reinterpret_cast<const float4*>(&src[i]);
  float4 b = *reinterpret_cast<const float4*>(&src[i + 4]);
  uint4 o;
  o.x = pk2(a.x, a.y); o.y = pk2(a.z, a.w);
  o.z = pk2(b.x, b.y); o.w = pk2(b.z, b.w);
  *reinterpret_cast<uint4*>(&dst[i]) = o;
}

// 7 fused transpose+convert jobs: W [Dc, J] fp32 -> WT [J, Dc] bf16.
struct TJobs {
  const float* src[7];
  ushort* dst[7];
  int J[7];
};
__global__ __launch_bounds__(256) void conv_transpose_multi(TJobs jobs) {
  const int job = blockIdx.z;
  const int J = jobs.J[job];
  const int h0 = blockIdx.y * 64;
  if (h0 >= J) return;
  const float* W = jobs.src[job];
  ushort* WT = jobs.dst[job];
  __shared__ float tile[64][65];
  const int d0 = blockIdx.x * 64;
  const int tid = threadIdx.x;
  #pragma unroll
  for (int i = 0; i < 16; i++) {
    int idx = tid + i * 256;
    int dd = idx >> 6, hh = idx & 63;
    tile[dd][hh] = W[(size_t)(d0 + dd) * J + h0 + hh];
  }
  __syncthreads();
  #pragma unroll
  for (int i = 0; i < 16; i++) {
    int idx = tid + i * 256;
    int hh = idx >> 6, dd = idx & 63;
    WT[(size_t)(h0 + hh) * Dc + d0 + dd] = f2bf(tile[dd][hh]);
  }
}

// C[m,n] = sum_k A[m,k]*BT[n,k]; bf16 in, fp32 or bf16 out (exactly one of Cf/Cbf).
// A [.,K] lda=K, BT [.,K] ldb=K. grid (N/64, M/64, batch), 256 thr, 64x64 tile.
__global__ __launch_bounds__(256) void gemm_bt(const ushort* __restrict__ A,
                                               const ushort* __restrict__ BT,
                                               float* __restrict__ Cf,
                                               ushort* __restrict__ Cbf,
                                               int K, int ldc,
                                               size_t sA, size_t sB, size_t sC) {
  const int bz = blockIdx.z;
  A  += (size_t)bz * sA;
  BT += (size_t)bz * sB;
  const int m0 = blockIdx.y * 64, n0 = blockIdx.x * 64;
  __shared__ __align__(16) ushort Asl[64][40];
  __shared__ __align__(16) ushort Bsl[64][40];
  const int tid = threadIdx.x, wave = tid >> 6, lane = tid & 63;
  const int quad = lane >> 4, l15 = lane & 15;
  const int wr = (wave & 1) * 32, wc = (wave >> 1) * 32;
  const int rSt = tid >> 2, kSt8 = (tid & 3) * 8;
  floatx4 acc[2][2];
  #pragma unroll
  for (int i = 0; i < 2; i++)
    #pragma unroll
    for (int j = 0; j < 2; j++) acc[i][j] = (floatx4){0.f, 0.f, 0.f, 0.f};
  uint4 pa = *reinterpret_cast<const uint4*>(&A[(size_t)(m0 + rSt) * K + kSt8]);
  uint4 pb = *reinterpret_cast<const uint4*>(&BT[(size_t)(n0 + rSt) * K + kSt8]);
  for (int k0 = 0; k0 < K; k0 += 32) {
    *reinterpret_cast<uint4*>(&Asl[rSt][kSt8]) = pa;
    *reinterpret_cast<uint4*>(&Bsl[rSt][kSt8]) = pb;
    __syncthreads();
    if (k0 + 32 < K) {
      pa = *reinterpret_cast<const uint4*>(&A[(size_t)(m0 + rSt) * K + k0 + 32 + kSt8]);
      pb = *reinterpret_cast<const uint4*>(&BT[(size_t)(n0 + rSt) * K + k0 + 32 + kSt8]);
    }
    short8 af[2], bb[2];
    #pragma unroll
    for (int i = 0; i < 2; i++)
      af[i] = *reinterpret_cast<const short8*>(&Asl[wr + i * 16 + l15][quad * 8]);
    #pragma unroll
    for (int j = 0; j < 2; j++)
      bb[j] = *reinterpret_cast<const short8*>(&Bsl[wc + j * 16 + l15][quad * 8]);
    #pragma unroll
    for (int i = 0; i < 2; i++)
      #pragma unroll
      for (int j = 0; j < 2; j++)
        acc[i][j] = __builtin_amdgcn_mfma_f32_16x16x32_bf16(af[i], bb[j], acc[i][j], 0, 0, 0);
    __syncthreads();
  }
  if (Cbf) {
    #pragma unroll
    for (int i = 0; i < 2; i++)
      #pragma unroll
      for (int j = 0; j < 2; j++)
        #pragma unroll
        for (int r = 0; r < 4; r++) {
          int row = m0 + wr + i * 16 + quad * 4 + r;
          int col = n0 + wc + j * 16 + l15;
          Cbf[(size_t)bz * sC + (size_t)row * ldc + col] = f2bf(acc[i][j][r]);
        }
  } else {
    #pragma unroll
    for (int i = 0; i < 2; i++)
      #pragma unroll
      for (int j = 0; j < 2; j++)
        #pragma unroll
        for (int r = 0; r < 4; r++) {
          int row = m0 + wr + i * 16 + quad * 4 + r;
          int col = n0 + wc + j * 16 + l15;
          Cf[(size_t)bz * sC + (size_t)row * ldc + col] = acc[i][j][r];
        }
  }
}

// Dot-attention scores, both directions in one dispatch (blockIdx.z selects).
// s[b,m,n] += sum_h v[h]*tanh( sum_d X[b,n,d]*Y[b,m,d]*Wd[d,h] ) via bf16 MFMA.
// Block: one (b,m), all 128 n, one 256-wide h half. grid (2, BM, 2).
// LDS double-buffered: stage slab k+1 while MFMA consumes slab k (1 barrier/slab).
__global__ __launch_bounds__(256, 2) void dot_scores_mfma3(const float* __restrict__ X0,
                                                           const float* __restrict__ X1,
                                                           const ushort* __restrict__ WdT1,
                                                           const ushort* __restrict__ WdT2,
                                                           const float* __restrict__ vd1,
                                                           const float* __restrict__ vd2,
                                                           float* __restrict__ Sd) {
  const int which = blockIdx.z;
  const float* X = which ? X1 : X0;
  const float* Y = which ? X0 : X1;
  const ushort* WdT = which ? WdT2 : WdT1;
  const float* v = which ? vd2 : vd1;
  float* S = Sd + (size_t)which * (BM * Nc);

  const int bm = blockIdx.y;
  const int b = bm >> 7;
  const int hBase = blockIdx.x * 256;
  const int tid = threadIdx.x;
  const int wave = tid >> 6, lane = tid & 63;
  const int quad = lane >> 4, l15 = lane & 15;
  const int wn = wave & 1, wh = wave >> 1;

  // manual LDS layout, 64 KB total -> 2 blocks/CU
  __shared__ __align__(16) char smraw[65536];
  ushort (*As0)[40] = (ushort(*)[40])(smraw);           // 128x40x2 = 10240
  ushort (*As1)[40] = (ushort(*)[40])(smraw + 10240);   // 10240
  ushort (*Bs0)[40] = (ushort(*)[40])(smraw + 20480);   // 256x40x2 = 20480
  ushort (*Bs1)[40] = (ushort(*)[40])(smraw + 40960);   // 20480
  float* yl = (float*)(smraw + 61440);                  // 4096
  float (*red)[33] = (float(*)[33])(smraw);             // 16896, aliases As0/As1 (post-loop)

  for (int i = tid; i < Dc; i += 256) yl[i] = Y[(size_t)bm * Dc + i];

  floatx4 acc[4][8];
  #pragma unroll
  for (int i = 0; i < 4; i++)
    #pragma unroll
    for (int j = 0; j < 8; j++) acc[i][j] = (floatx4){0.f, 0.f, 0.f, 0.f};

  const float* Xb = X + (size_t)b * Nc * Dc;
  const int nSt = tid >> 2;
  const int kSt4 = (tid & 3) * 4;
  const int kSt8 = (tid & 3) * 8;

  auto stage = [&](int k0, ushort (*Asb)[40], ushort (*Bsb)[40]) {
    #pragma unroll
    for (int u2 = 0; u2 < 4; u2++) {
      const int n = (u2 >> 1) * 64 + nSt;
      const int kc = (u2 & 1) * 16 + kSt4;
      float4 xv = *reinterpret_cast<const float4*>(&Xb[(size_t)n * Dc + k0 + kc]);
      float4 yv = *reinterpret_cast<const float4*>(&yl[k0 + kc]);
      uint2 o;
      o.x = pk2(xv.x * yv.x, xv.y * yv.y);
      o.y = pk2(xv.z * yv.z, xv.w * yv.w);
      *reinterpret_cast<uint2*>(&Asb[n][kc]) = o;
    }
    #pragma unroll
    for (int r = 0; r < 4; r++)
      *reinterpret_cast<uint4*>(&Bsb[r * 64 + nSt][kSt8]) =
          *reinterpret_cast<const uint4*>(&WdT[(size_t)(hBase + r * 64 + nSt) * Dc + k0 + kSt8]);
  };

  auto mfma_step = [&](ushort (*Asb)[40], ushort (*Bsb)[40]) {
    short8 af[4], bfr[8];
    #pragma unroll
    for (int i = 0; i < 4; i++)
      af[i] = *reinterpret_cast<const short8*>(&Asb[wn * 64 + i * 16 + l15][quad * 8]);
    #pragma unroll
    for (int j = 0; j < 8; j++)
      bfr[j] = *reinterpret_cast<const short8*>(&Bsb[wh * 128 + j * 16 + l15][quad * 8]);
    #pragma unroll
    for (int i = 0; i < 4; i++)
      #pragma unroll
      for (int j = 0; j < 8; j++)
        acc[i][j] = __builtin_amdgcn_mfma_f32_16x16x32_bf16(af[i], bfr[j], acc[i][j], 0, 0, 0);
  };

  __syncthreads();          // yl ready
  stage(0, As0, Bs0);
  __syncthreads();
  #pragma unroll 1
  for (int s = 0; s < 32; s += 2) {
    if (s + 1 < 32) stage((s + 1) * 32, As1, Bs1);
    mfma_step(As0, Bs0);
    __syncthreads();
    if (s + 2 < 32) stage((s + 2) * 32, As0, Bs0);
    mfma_step(As1, Bs1);
    __syncthreads();
  }

  // epilogue: p[n] = sum over this wave's 128 h of v[h]*tanh(z[n,h])
  float vv[8];
  #pragma unroll
  for (int j = 0; j < 8; j++) vv[j] = v[hBase + wh * 128 + j * 16 + l15];
  #pragma unroll
  for (int i = 0; i < 4; i++)
    #pragma unroll
    for (int r = 0; r < 4; r++) {
      float p = 0.f;
      #pragma unroll
      for (int j = 0; j < 8; j++) p = fmaf(vv[j], fast_tanh(acc[i][j][r]), p);
      red[wn * 64 + i * 16 + quad * 4 + r][wh * 16 + l15] = p;
    }
  __syncthreads();
  if (tid < 128) {
    float s = 0.f;
    #pragma unroll
    for (int c = 0; c < 32; c++) s += red[tid][c];
    atomicAdd(&S[(size_t)bm * Nc + tid], s);
  }
}

// s[b,m,n] = sum_h v[h]*tanh(Arow[b,n,:] + sign*Brow[b,m,:]) tiled 16m x 16n x 512h.
// grid (8 nt, 8 mt, B), 256 thr. Arow/Brow are projection bases (row stride = rs).
__global__ __launch_bounds__(256) void addtanh_tiled(const float* __restrict__ Arow,
                                                     const float* __restrict__ Brow,
                                                     const float* __restrict__ v,
                                                     float sign, float* __restrict__ S,
                                                     int rs) {
  const int nt = blockIdx.x, mt = blockIdx.y, b = blockIdx.z;
  __shared__ __align__(16) float at[16][516];
  __shared__ __align__(16) float bt2[16][516];
  __shared__ __align__(16) float vl[512];
  const int tid = threadIdx.x;
  #pragma unroll
  for (int p = 0; p < 8; p++) {
    int idx = p * 256 + tid;
    int r = idx >> 7, c4 = (idx & 127) * 4;
    *reinterpret_cast<float4*>(&at[r][c4]) =
        *reinterpret_cast<const float4*>(&Arow[(size_t)(b * Nc + nt * 16 + r) * rs + c4]);
    *reinterpret_cast<float4*>(&bt2[r][c4]) =
        *reinterpret_cast<const float4*>(&Brow[(size_t)(b * Nc + mt * 16 + r) * rs + c4]);
  }
  if (tid < 128)
    *reinterpret_cast<float4*>(&vl[tid * 4]) = *reinterpret_cast<const float4*>(&v[tid * 4]);
  __syncthreads();
  const int m = tid >> 4, n = tid & 15;
  float acc = 0.f;
  #pragma unroll 4
  for (int c = 0; c < 512; c += 4) {
    float4 av = *reinterpret_cast<const float4*>(&at[n][c]);
    float4 bv = *reinterpret_cast<const float4*>(&bt2[m][c]);
    float4 vv = *reinterpret_cast<const float4*>(&vl[c]);
    acc = fmaf(vv.x, fast_tanh(fmaf(sign, bv.x, av.x)), acc);
    acc = fmaf(vv.y, fast_tanh(fmaf(sign, bv.y, av.y)), acc);
    acc = fmaf(vv.z, fast_tanh(fmaf(sign, bv.z, av.z)), acc);
    acc = fmaf(vv.w, fast_tanh(fmaf(sign, bv.w, av.w)), acc);
  }
  S[(size_t)(b * Nc + mt * 16 + m) * Nc + nt * 16 + n] = acc;
}

// in-place softmax over last dim (=128); one row per block, 128 threads
__global__ __launch_bounds__(128) void softmax128(float* __restrict__ S) {
  const int row = blockIdx.x;
  const int tid = threadIdx.x;
  float x = S[(size_t)row * 128 + tid];
  __shared__ float mbuf[2], sbuf[2];
  float mx = x;
  #pragma unroll
  for (int o = 32; o; o >>= 1) mx = fmaxf(mx, __shfl_down(mx, o, 64));
  if ((tid & 63) == 0) mbuf[tid >> 6] = mx;
  __syncthreads();
  mx = fmaxf(mbuf[0], mbuf[1]);
  float e = __expf(x - mx);
  float sm = e;
  #pragma unroll
  for (int o = 32; o; o >>= 1) sm += __shfl_down(sm, o, 64);
  if ((tid & 63) == 0) sbuf[tid >> 6] = sm;
  __syncthreads();
  sm = sbuf[0] + sbuf[1];
  S[(size_t)row * 128 + tid] = e / sm;
}

#define FMA4(acc, s, v)                  \
  acc.x = fmaf(s, v.x, acc.x);           \
  acc.y = fmaf(s, v.y, acc.y);           \
  acc.z = fmaf(s, v.z, acc.z);           \
  acc.w = fmaf(s, v.w, acc.w)

// agg[b,m,d] = max(x1[b,m,d], qtc, qtb, qts, qtd, qtm); grid (BM), 256 threads x 4 d each
__global__ __launch_bounds__(256) void agg_max(const float* __restrict__ x0,
                                               const float* __restrict__ x1,
                                               const float* __restrict__ Sc,
                                               const float* __restrict__ Sb,
                                               const float* __restrict__ Sd1,
                                               const float* __restrict__ Sd2,
                                               const float* __restrict__ Sm,
                                               float* __restrict__ agg) {
  const int bm = blockIdx.x;
  const int b = bm >> 7;
  const int tid = threadIdx.x;
  __shared__ float w[5][128];
  if (tid < 128) {
    w[0][tid] = Sc[(size_t)bm * Nc + tid];
    w[1][tid] = Sb[(size_t)bm * Nc + tid];
    w[2][tid] = Sd1[(size_t)bm * Nc + tid];
    w[3][tid] = Sd2[(size_t)bm * Nc + tid];
    w[4][tid] = Sm[(size_t)bm * Nc + tid];
  }
  __syncthreads();
  const int d0 = tid * 4;
  float4 qc = {0, 0, 0, 0}, qb = {0, 0, 0, 0}, qs = {0, 0, 0, 0};
  float4 qd = {0, 0, 0, 0}, qm = {0, 0, 0, 0};
  const float* X0b = x0 + (size_t)b * Nc * Dc;
  const float* X1b = x1 + (size_t)b * Nc * Dc;
  for (int n = 0; n < Nc; n++) {
    float4 xv = *reinterpret_cast<const float4*>(&X0b[(size_t)n * Dc + d0]);
    float4 yv = *reinterpret_cast<const float4*>(&X1b[(size_t)n * Dc + d0]);
    float wc = w[0][n], wb = w[1][n], ws = w[2][n], wd = w[3][n], wm = w[4][n];
    FMA4(qc, wc, xv);
    FMA4(qb, wb, xv);
    FMA4(qs, ws, xv);
    FMA4(qd, wd, yv);
    FMA4(qm, wm, xv);
  }
  float4 x1v = *reinterpret_cast<const float4*>(&x1[(size_t)bm * Dc + d0]);
  float4 r;
  r.x = fmaxf(x1v.x, fmaxf(fmaxf(qs.x, qc.x), fmaxf(fmaxf(qd.x, qb.x), qm.x)));
  r.y = fmaxf(x1v.y, fmaxf(fmaxf(qs.y, qc.y), fmaxf(fmaxf(qd.y, qb.y), qm.y)));
  r.z = fmaxf(x1v.z, fmaxf(fmaxf(qs.z, qc.z), fmaxf(fmaxf(qd.z, qb.z), qm.z)));
  r.w = fmaxf(x1v.w, fmaxf(fmaxf(qs.w, qc.w), fmaxf(fmaxf(qd.w, qb.w), qm.w)));
  *reinterpret_cast<float4*>(&agg[(size_t)bm * Dc + d0]) = r;
}

// u[d2] = sum_h Wp1[d2,h]*vp[h]; grid (2*Dc), 64 threads
__global__ __launch_bounds__(64) void compute_u(const float* __restrict__ Wp1,
                                                const float* __restrict__ vp,
                                                float* __restrict__ u) {
  const int d2 = blockIdx.x;
  const int tid = threadIdx.x;
  float p = 0.f;
  #pragma unroll
  for (int h = tid; h < Hc; h += 64) p = fmaf(Wp1[(size_t)d2 * Hc + h], vp[h], p);
  #pragma unroll
  for (int o = 32; o; o >>= 1) p += __shfl_down(p, o, 64);
  if (tid == 0) u[d2] = p;
}

// score[bm] = x1[bm,:].u[0:D] + agg[bm,:].u[D:2D]   (rq@Wp2 term is softmax-invariant)
__global__ __launch_bounds__(256) void final_scores(const float* __restrict__ x1,
                                                    const float* __restrict__ agg,
                                                    const float* __restrict__ u,
                                                    float* __restrict__ score) {
  const int bm = blockIdx.x;
  const int tid = threadIdx.x;
  float p = 0.f;
  #pragma unroll
  for (int d = tid; d < Dc; d += 256)
    p = fmaf(x1[(size_t)bm * Dc + d], u[d], fmaf(agg[(size_t)bm * Dc + d], u[Dc + d], p));
  __shared__ float buf4[4];
  p = block_sum256(p, buf4);
  if (tid == 0) score[bm] = p;
}

// softmax over raw scores (inline) + out[b,j] = relu(sum_m sp[m]*cat[b,m,:].Wpred[:,j]+bpred)
__global__ __launch_bounds__(256) void final_out(const float* __restrict__ x1,
                                                 const float* __restrict__ agg,
                                                 const float* __restrict__ score,
                                                 const float* __restrict__ Wpred,
                                                 const float* __restrict__ bpred,
                                                 float* __restrict__ out) {
  const int b = blockIdx.x;
  const int tid = threadIdx.x;
  __shared__ float spL[128];
  __shared__ float mbuf[2], sbuf[2];
  // inline softmax over the 128 scores of this batch (waves 0-1 only)
  if (tid < 128) {
    float x = score[b * Nc + tid];
    float mx = x;
    #pragma unroll
    for (int o = 32; o; o >>= 1) mx = fmaxf(mx, __shfl_down(mx, o, 64));
    if ((tid & 63) == 0) mbuf[tid >> 6] = mx;
  }
  __syncthreads();
  if (tid < 128) {
    float x = score[b * Nc + tid];
    float mx = fmaxf(mbuf[0], mbuf[1]);
    float e = __expf(x - mx);
    float sm = e;
    #pragma unroll
    for (int o = 32; o; o >>= 1) sm += __shfl_down(sm, o, 64);
    if ((tid & 63) == 0) sbuf[tid >> 6] = sm;
    spL[tid] = e;
  }
  __syncthreads();
  const float inv = 1.f / (sbuf[0] + sbuf[1]);
  const int d2 = tid * 8;
  float w0[8], w1[8];
  #pragma unroll
  for (int i = 0; i < 8; i++) {
    w0[i] = Wpred[(size_t)(d2 + i) * 2 + 0];
    w1[i] = Wpred[(size_t)(d2 + i) * 2 + 1];
  }
  const float* src = (d2 < Dc) ? (x1 + (size_t)b * Nc * Dc + d2)
                               : (agg + (size_t)b * Nc * Dc + (d2 - Dc));
  float p0 = 0.f, p1 = 0.f;
  for (int m = 0; m < Nc; m++) {
    float s = spL[m] * inv;
    const float* r = src + (size_t)m * Dc;
    #pragma unroll
    for (int i = 0; i < 8; i++) {
      float sc = s * r[i];
      p0 = fmaf(sc, w0[i], p0);
      p1 = fmaf(sc, w1[i], p1);
    }
  }
  #pragma unroll
  for (int o = 32; o; o >>= 1) {
    p0 += __shfl_down(p0, o, 64);
    p1 += __shfl_down(p1, o, 64);
  }
  __shared__ float r0[4], r1[4];
  const int w = tid >> 6, lane = tid & 63;
  if (lane == 0) { r0[w] = p0; r1[w] = p1; }
  __syncthreads();
  if (tid == 0) {
    float q0 = r0[0] + r0[1] + r0[2] + r0[3] + bpred[0];
    float q1 = r1[0] + r1[1] + r1[2] + r1[3] + bpred[1];
    out[b * 2 + 0] = fmaxf(q0, 0.f);
    out[b * 2 + 1] = fmaxf(q1, 0.f);
  }
}

extern "C" void kernel_launch(void* const* d_in, const int* in_sizes, int n_in,
                              void* d_out, int out_size, void* d_ws, size_t ws_size,
                              hipStream_t stream) {
  const float* x0    = (const float*)d_in[0];
  const float* x1    = (const float*)d_in[1];
  const float* Wc1   = (const float*)d_in[2];
  const float* Wc2   = (const float*)d_in[3];
  const float* vc    = (const float*)d_in[4];
  const float* Wb    = (const float*)d_in[5];
  const float* Wd1   = (const float*)d_in[6];
  const float* vd1   = (const float*)d_in[7];
  const float* Wd2   = (const float*)d_in[8];
  const float* vd2   = (const float*)d_in[9];
  const float* Wm    = (const float*)d_in[10];
  const float* vm    = (const float*)d_in[11];
  // d_in[12]=Wq, d_in[13]=vq, d_in[15]=Wp2: provably dead (softmax shift-invariance)
  const float* Wp1   = (const float*)d_in[14];
  const float* vp    = (const float*)d_in[16];
  const float* Wpred = (const float*)d_in[17];
  const float* bpred = (const float*)d_in[18];
  float* out = (float*)d_out;

  float* ws = (float*)d_ws;
  float* C1     = ws;               // [BM, 2H] fp32 (x0@[Wc1|Wm]); aliased as agg later
  float* C2     = C1 + 1048576;     // [BM, 2H] fp32 (x1@[Wc2|Wm])
  float* sc     = C2 + 1048576;     // 5 contiguous score tensors [B,M,N] = 131072 each
  float* sb     = sc + 131072;
  float* sd1    = sb + 131072;
  float* sd2    = sd1 + 131072;
  float* smv    = sd2 + 131072;
  float* u      = smv + 131072;     // [2D]
  float* score2 = u + 2048;         // [B*M]
  ushort* x0bf  = (ushort*)(score2 + 1024);   // [BM, D] bf16
  ushort* x1bf  = x0bf + 1048576;
  ushort* W1T   = x1bf + 1048576;   // [2H=1024, D] bf16: rows 0-511 Wc1^T, 512-1023 Wm^T
  ushort* W2T   = W1T + 1048576;    // rows 0-511 Wc2^T, 512-1023 Wm^T
  ushort* WbT   = W2T + 1048576;    // [D, D] bf16 (Wb^T)
  ushort* xWbbf = WbT + 1048576;    // [BM, D] bf16 (x0@Wb)
  ushort* wdT1  = xWbbf + 1048576;  // [H, D] bf16
  ushort* wdT2  = wdT1 + 524288;
  float* agg    = C1;               // alias: C1 dead after addtanh_tiled; agg written after
  // total ~25.7 MB

  // --- input/weight conversion (2 launches) ---
  cvt_both<<<1024, 256, 0, stream>>>(x0, x1, x0bf, x1bf);
  TJobs tj;
  tj.src[0] = Wd1; tj.dst[0] = wdT1;            tj.J[0] = Hc;
  tj.src[1] = Wd2; tj.dst[1] = wdT2;            tj.J[1] = Hc;
  tj.src[2] = Wc1; tj.dst[2] = W1T;             tj.J[2] = Hc;
  tj.src[3] = Wm;  tj.dst[3] = W1T + 512 * Dc;  tj.J[3] = Hc;
  tj.src[4] = Wc2; tj.dst[4] = W2T;             tj.J[4] = Hc;
  tj.src[5] = Wm;  tj.dst[5] = W2T + 512 * Dc;  tj.J[5] = Hc;
  tj.src[6] = Wb;  tj.dst[6] = WbT;             tj.J[6] = Dc;
  conv_transpose_multi<<<dim3(16, 16, 7), 256, 0, stream>>>(tj);

  // --- projections (bf16 MFMA) ---
  gemm_bt<<<dim3(16, 16, 1), 256, 0, stream>>>(x0bf, W1T, C1, nullptr, Dc, 1024, 0, 0, 0);
  gemm_bt<<<dim3(16, 16, 1), 256, 0, stream>>>(x1bf, W2T, C2, nullptr, Dc, 1024, 0, 0, 0);
  gemm_bt<<<dim3(16, 16, 1), 256, 0, stream>>>(x0bf, WbT, nullptr, xWbbf, Dc, 1024, 0, 0, 0);
  // bilinear scores: sb[b,m,n] = x1[b,m,:].xWb[b,n,:]
  gemm_bt<<<dim3(2, 2, 8), 256, 0, stream>>>(x1bf, xWbbf, sb, nullptr, Dc, 128,
                                             131072, 131072, 16384);

  // --- concat / minus scores (tiled tanh) ---
  addtanh_tiled<<<dim3(8, 8, 8), 256, 0, stream>>>(C1, C2, vc, 1.f, sc, 1024);
  addtanh_tiled<<<dim3(8, 8, 8), 256, 0, stream>>>(C1 + 512, C2 + 512, vm, -1.f, smv, 1024);

  // --- dot scores (bf16 MFMA, LDS double-buffered, both directions) ---
  (void)hipMemsetAsync(sd1, 0, 2 * 131072 * sizeof(float), stream);
  dot_scores_mfma3<<<dim3(2, BM, 2), 256, 0, stream>>>(x0, x1, wdT1, wdT2, vd1, vd2, sd1);

  // --- softmax over n for all 5 score tensors (contiguous rows) ---
  softmax128<<<5 * BM, 128, 0, stream>>>(sc);

  // --- weighted sums + elementwise max (agg aliases C1) ---
  agg_max<<<BM, 256, 0, stream>>>(x0, x1, sc, sb, sd1, sd2, smv, agg);

  // --- aggregation (rq path dropped; Wp1@vp prefolded; softmax fused into final_out) ---
  compute_u<<<2 * Dc, 64, 0, stream>>>(Wp1, vp, u);
  final_scores<<<BM, 256, 0, stream>>>(x1, agg, u, score2);
  final_out<<<Bc, 256, 0, stream>>>(x1, agg, score2, Wpred, bpred, out);
}

// Round 8
// 651.035 us; speedup vs baseline: 8.0332x; 1.0769x over previous
//
#include <hip/hip_runtime.h>
#include <hip/hip_bf16.h>

// Shapes (fixed by the reference): B=8, N=M=128, D=1024, H=512
static constexpr int Bc = 8, Nc = 128, Dc = 1024, Hc = 512;
static constexpr int BM = Bc * Nc;  // 1024

typedef _Float16 half8 __attribute__((ext_vector_type(8)));
typedef __fp16 fp16x2 __attribute__((ext_vector_type(2)));
typedef float floatx4 __attribute__((ext_vector_type(4)));

__device__ __forceinline__ float fast_tanh(float x) {
  x = fminf(fmaxf(x, -15.f), 15.f);
  float e = __expf(2.f * x);
  return (e - 1.f) / (e + 1.f);
}

__device__ __forceinline__ unsigned pkh2(float a, float b) {  // packed fp16 pair (RTZ)
  fp16x2 h = __builtin_amdgcn_cvt_pkrtz(a, b);
  return __builtin_bit_cast(unsigned, h);
}

__device__ __forceinline__ ushort f2h(float f) {  // fp32 -> fp16 (RNE)
  _Float16 h = (_Float16)f;
  return __builtin_bit_cast(ushort, h);
}

// sum over 256-thread block; result broadcast to all threads
__device__ __forceinline__ float block_sum256(float v, float* buf4) {
  #pragma unroll
  for (int o = 32; o; o >>= 1) v += __shfl_down(v, o, 64);
  const int w = threadIdx.x >> 6, lane = threadIdx.x & 63;
  if (lane == 0) buf4[w] = v;
  __syncthreads();
  return buf4[0] + buf4[1] + buf4[2] + buf4[3];
}

// fp32 -> fp16 for x0 (blocks 0-511) and x1 (512-1023); each block converts 2048 elems
__global__ __launch_bounds__(256) void cvt_both(const float* __restrict__ x0,
                                                const float* __restrict__ x1,
                                                ushort* __restrict__ o0,
                                                ushort* __restrict__ o1) {
  int bi = blockIdx.x;
  const float* src = (bi < 512) ? x0 : x1;
  ushort* dst = (bi < 512) ? o0 : o1;
  int off = (bi & 511);
  int i = (off * 256 + threadIdx.x) * 8;
  float4 a = *reinterpret_cast<const float4*>(&src[i]);
  float4 b = *reinterpret_cast<const float4*>(&src[i + 4]);
  uint4 o;
  o.x = pkh2(a.x, a.y); o.y = pkh2(a.z, a.w);
  o.z = pkh2(b.x, b.y); o.w = pkh2(b.z, b.w);
  *reinterpret_cast<uint4*>(&dst[i]) = o;
}

// 7 fused transpose+convert jobs: W [Dc, J] fp32 -> WT [J, Dc] fp16.
struct TJobs {
  const float* src[7];
  ushort* dst[7];
  int J[7];
};
__global__ __launch_bounds__(256) void conv_transpose_multi(TJobs jobs) {
  const int job = blockIdx.z;
  const int J = jobs.J[job];
  const int h0 = blockIdx.y * 64;
  if (h0 >= J) return;
  const float* W = jobs.src[job];
  ushort* WT = jobs.dst[job];
  __shared__ float tile[64][65];
  const int d0 = blockIdx.x * 64;
  const int tid = threadIdx.x;
  #pragma unroll
  for (int i = 0; i < 16; i++) {
    int idx = tid + i * 256;
    int dd = idx >> 6, hh = idx & 63;
    tile[dd][hh] = W[(size_t)(d0 + dd) * J + h0 + hh];
  }
  __syncthreads();
  #pragma unroll
  for (int i = 0; i < 16; i++) {
    int idx = tid + i * 256;
    int hh = idx >> 6, dd = idx & 63;
    WT[(size_t)(h0 + hh) * Dc + d0 + dd] = f2h(tile[dd][hh]);
  }
}

// C[m,n] = sum_k A[m,k]*BT[n,k]; fp16 in, fp32 or fp16 out (exactly one of Cf/Ch).
// A [.,K] lda=K, BT [.,K] ldb=K. grid (N/64, M/64, batch), 256 thr, 64x64 tile.
__global__ __launch_bounds__(256) void gemm_bt(const ushort* __restrict__ A,
                                               const ushort* __restrict__ BT,
                                               float* __restrict__ Cf,
                                               ushort* __restrict__ Ch,
                                               int K, int ldc,
                                               size_t sA, size_t sB, size_t sC) {
  const int bz = blockIdx.z;
  A  += (size_t)bz * sA;
  BT += (size_t)bz * sB;
  const int m0 = blockIdx.y * 64, n0 = blockIdx.x * 64;
  __shared__ __align__(16) ushort Asl[64][40];
  __shared__ __align__(16) ushort Bsl[64][40];
  const int tid = threadIdx.x, wave = tid >> 6, lane = tid & 63;
  const int quad = lane >> 4, l15 = lane & 15;
  const int wr = (wave & 1) * 32, wc = (wave >> 1) * 32;
  const int rSt = tid >> 2, kSt8 = (tid & 3) * 8;
  floatx4 acc[2][2];
  #pragma unroll
  for (int i = 0; i < 2; i++)
    #pragma unroll
    for (int j = 0; j < 2; j++) acc[i][j] = (floatx4){0.f, 0.f, 0.f, 0.f};
  uint4 pa = *reinterpret_cast<const uint4*>(&A[(size_t)(m0 + rSt) * K + kSt8]);
  uint4 pb = *reinterpret_cast<const uint4*>(&BT[(size_t)(n0 + rSt) * K + kSt8]);
  for (int k0 = 0; k0 < K; k0 += 32) {
    *reinterpret_cast<uint4*>(&Asl[rSt][kSt8]) = pa;
    *reinterpret_cast<uint4*>(&Bsl[rSt][kSt8]) = pb;
    __syncthreads();
    if (k0 + 32 < K) {
      pa = *reinterpret_cast<const uint4*>(&A[(size_t)(m0 + rSt) * K + k0 + 32 + kSt8]);
      pb = *reinterpret_cast<const uint4*>(&BT[(size_t)(n0 + rSt) * K + k0 + 32 + kSt8]);
    }
    half8 af[2], bb[2];
    #pragma unroll
    for (int i = 0; i < 2; i++)
      af[i] = *reinterpret_cast<const half8*>(&Asl[wr + i * 16 + l15][quad * 8]);
    #pragma unroll
    for (int j = 0; j < 2; j++)
      bb[j] = *reinterpret_cast<const half8*>(&Bsl[wc + j * 16 + l15][quad * 8]);
    #pragma unroll
    for (int i = 0; i < 2; i++)
      #pragma unroll
      for (int j = 0; j < 2; j++)
        acc[i][j] = __builtin_amdgcn_mfma_f32_16x16x32_f16(af[i], bb[j], acc[i][j], 0, 0, 0);
    __syncthreads();
  }
  if (Ch) {
    #pragma unroll
    for (int i = 0; i < 2; i++)
      #pragma unroll
      for (int j = 0; j < 2; j++)
        #pragma unroll
        for (int r = 0; r < 4; r++) {
          int row = m0 + wr + i * 16 + quad * 4 + r;
          int col = n0 + wc + j * 16 + l15;
          Ch[(size_t)bz * sC + (size_t)row * ldc + col] = f2h(acc[i][j][r]);
        }
  } else {
    #pragma unroll
    for (int i = 0; i < 2; i++)
      #pragma unroll
      for (int j = 0; j < 2; j++)
        #pragma unroll
        for (int r = 0; r < 4; r++) {
          int row = m0 + wr + i * 16 + quad * 4 + r;
          int col = n0 + wc + j * 16 + l15;
          Cf[(size_t)bz * sC + (size_t)row * ldc + col] = acc[i][j][r];
        }
  }
}

// Dot-attention scores, both directions in one dispatch (blockIdx.z selects).
// s[b,m,n] += sum_h v[h]*tanh( sum_d X[b,n,d]*Y[b,m,d]*Wd[d,h] ) via fp16 MFMA.
// Block: one (b,m), all 128 n, one 256-wide h half. grid (2, BM, 2).
// A-tile built with v_pk_mul_f16 from pre-converted fp16 x; LDS double-buffered.
__global__ __launch_bounds__(256, 2) void dot_scores_mfma4(const ushort* __restrict__ X0h,
                                                           const ushort* __restrict__ X1h,
                                                           const ushort* __restrict__ WdT1,
                                                           const ushort* __restrict__ WdT2,
                                                           const float* __restrict__ vd1,
                                                           const float* __restrict__ vd2,
                                                           float* __restrict__ Sd) {
  const int which = blockIdx.z;
  const ushort* Xh = which ? X1h : X0h;
  const ushort* Yh = which ? X0h : X1h;
  const ushort* WdT = which ? WdT2 : WdT1;
  const float* v = which ? vd2 : vd1;
  float* S = Sd + (size_t)which * (BM * Nc);

  const int bm = blockIdx.y;
  const int b = bm >> 7;
  const int hBase = blockIdx.x * 256;
  const int tid = threadIdx.x;
  const int wave = tid >> 6, lane = tid & 63;
  const int quad = lane >> 4, l15 = lane & 15;
  const int wn = wave & 1, wh = wave >> 1;

  // manual LDS layout, 64 KB -> 2 blocks/CU
  __shared__ __align__(16) char smraw[65536];
  ushort (*As0)[40] = (ushort(*)[40])(smraw);           // 128x40x2 = 10240
  ushort (*As1)[40] = (ushort(*)[40])(smraw + 10240);   // 10240
  ushort (*Bs0)[40] = (ushort(*)[40])(smraw + 20480);   // 256x40x2 = 20480
  ushort (*Bs1)[40] = (ushort(*)[40])(smraw + 40960);   // 20480
  ushort* ylh = (ushort*)(smraw + 61440);               // 2048 (fp16 y row)
  float (*red)[33] = (float(*)[33])(smraw);             // 16896, aliases As (post-loop)

  {  // y row: already fp16 in global, plain copy
    const uint* Yrow = (const uint*)(Yh + (size_t)bm * Dc);
    uint* dst = (uint*)ylh;
    for (int i = tid; i < Dc / 2; i += 256) dst[i] = Yrow[i];
  }

  floatx4 acc[4][8];
  #pragma unroll
  for (int i = 0; i < 4; i++)
    #pragma unroll
    for (int j = 0; j < 8; j++) acc[i][j] = (floatx4){0.f, 0.f, 0.f, 0.f};

  const ushort* Xb = Xh + (size_t)b * Nc * Dc;
  const int nSt = tid >> 2;          // 0..63
  const int kSt8 = (tid & 3) * 8;    // 8-half chunk within 32-wide slab

  auto stage = [&](int k0, ushort (*Asb)[40], ushort (*Bsb)[40]) {
    half8 yv = *reinterpret_cast<const half8*>(&ylh[k0 + kSt8]);
    #pragma unroll
    for (int p = 0; p < 2; p++) {
      const int n = p * 64 + nSt;
      half8 xv = *reinterpret_cast<const half8*>(&Xb[(size_t)n * Dc + k0 + kSt8]);
      half8 prod = xv * yv;  // 4x v_pk_mul_f16
      *reinterpret_cast<half8*>(&Asb[n][kSt8]) = prod;
    }
    #pragma unroll
    for (int r = 0; r < 4; r++)
      *reinterpret_cast<uint4*>(&Bsb[r * 64 + nSt][kSt8]) =
          *reinterpret_cast<const uint4*>(&WdT[(size_t)(hBase + r * 64 + nSt) * Dc + k0 + kSt8]);
  };

  auto mfma_step = [&](ushort (*Asb)[40], ushort (*Bsb)[40]) {
    half8 af[4], bfr[8];
    #pragma unroll
    for (int i = 0; i < 4; i++)
      af[i] = *reinterpret_cast<const half8*>(&Asb[wn * 64 + i * 16 + l15][quad * 8]);
    #pragma unroll
    for (int j = 0; j < 8; j++)
      bfr[j] = *reinterpret_cast<const half8*>(&Bsb[wh * 128 + j * 16 + l15][quad * 8]);
    #pragma unroll
    for (int i = 0; i < 4; i++)
      #pragma unroll
      for (int j = 0; j < 8; j++)
        acc[i][j] = __builtin_amdgcn_mfma_f32_16x16x32_f16(af[i], bfr[j], acc[i][j], 0, 0, 0);
  };

  __syncthreads();          // ylh ready
  stage(0, As0, Bs0);
  __syncthreads();
  #pragma unroll 1
  for (int s = 0; s < 32; s += 2) {
    if (s + 1 < 32) stage((s + 1) * 32, As1, Bs1);
    mfma_step(As0, Bs0);
    __syncthreads();
    if (s + 2 < 32) stage((s + 2) * 32, As0, Bs0);
    mfma_step(As1, Bs1);
    __syncthreads();
  }

  // epilogue: p[n] = sum over this wave's 128 h of v[h]*tanh(z[n,h])
  float vv[8];
  #pragma unroll
  for (int j = 0; j < 8; j++) vv[j] = v[hBase + wh * 128 + j * 16 + l15];
  #pragma unroll
  for (int i = 0; i < 4; i++)
    #pragma unroll
    for (int r = 0; r < 4; r++) {
      float p = 0.f;
      #pragma unroll
      for (int j = 0; j < 8; j++) p = fmaf(vv[j], fast_tanh(acc[i][j][r]), p);
      red[wn * 64 + i * 16 + quad * 4 + r][wh * 16 + l15] = p;
    }
  __syncthreads();
  if (tid < 128) {
    float s = 0.f;
    #pragma unroll
    for (int c = 0; c < 32; c++) s += red[tid][c];
    atomicAdd(&S[(size_t)bm * Nc + tid], s);
  }
}

// concat (z<8) and minus (z>=8) scores in one dispatch; tile 16m x 16n x 512h.
// grid (8 nt, 8 mt, 16), 256 thr.
__global__ __launch_bounds__(256) void addtanh_tiled2(const float* __restrict__ C1,
                                                      const float* __restrict__ C2,
                                                      const float* __restrict__ vc,
                                                      const float* __restrict__ vm,
                                                      float* __restrict__ Sc,
                                                      float* __restrict__ Sm) {
  const int nt = blockIdx.x, mt = blockIdx.y;
  const int which = blockIdx.z >> 3, b = blockIdx.z & 7;
  const float* Arow = C1 + which * 512;
  const float* Brow = C2 + which * 512;
  const float* v = which ? vm : vc;
  const float sign = which ? -1.f : 1.f;
  float* S = which ? Sm : Sc;
  __shared__ __align__(16) float at[16][516];
  __shared__ __align__(16) float bt2[16][516];
  __shared__ __align__(16) float vl[512];
  const int tid = threadIdx.x;
  #pragma unroll
  for (int p = 0; p < 8; p++) {
    int idx = p * 256 + tid;
    int r = idx >> 7, c4 = (idx & 127) * 4;
    *reinterpret_cast<float4*>(&at[r][c4]) =
        *reinterpret_cast<const float4*>(&Arow[(size_t)(b * Nc + nt * 16 + r) * 1024 + c4]);
    *reinterpret_cast<float4*>(&bt2[r][c4]) =
        *reinterpret_cast<const float4*>(&Brow[(size_t)(b * Nc + mt * 16 + r) * 1024 + c4]);
  }
  if (tid < 128)
    *reinterpret_cast<float4*>(&vl[tid * 4]) = *reinterpret_cast<const float4*>(&v[tid * 4]);
  __syncthreads();
  const int m = tid >> 4, n = tid & 15;
  float acc = 0.f;
  #pragma unroll 4
  for (int c = 0; c < 512; c += 4) {
    float4 av = *reinterpret_cast<const float4*>(&at[n][c]);
    float4 bv = *reinterpret_cast<const float4*>(&bt2[m][c]);
    float4 vv = *reinterpret_cast<const float4*>(&vl[c]);
    acc = fmaf(vv.x, fast_tanh(fmaf(sign, bv.x, av.x)), acc);
    acc = fmaf(vv.y, fast_tanh(fmaf(sign, bv.y, av.y)), acc);
    acc = fmaf(vv.z, fast_tanh(fmaf(sign, bv.z, av.z)), acc);
    acc = fmaf(vv.w, fast_tanh(fmaf(sign, bv.w, av.w)), acc);
  }
  S[(size_t)(b * Nc + mt * 16 + m) * Nc + nt * 16 + n] = acc;
}

// in-place softmax over last dim (=128); one row per block, 128 threads
__global__ __launch_bounds__(128) void softmax128(float* __restrict__ S) {
  const int row = blockIdx.x;
  const int tid = threadIdx.x;
  float x = S[(size_t)row * 128 + tid];
  __shared__ float mbuf[2], sbuf[2];
  float mx = x;
  #pragma unroll
  for (int o = 32; o; o >>= 1) mx = fmaxf(mx, __shfl_down(mx, o, 64));
  if ((tid & 63) == 0) mbuf[tid >> 6] = mx;
  __syncthreads();
  mx = fmaxf(mbuf[0], mbuf[1]);
  float e = __expf(x - mx);
  float sm = e;
  #pragma unroll
  for (int o = 32; o; o >>= 1) sm += __shfl_down(sm, o, 64);
  if ((tid & 63) == 0) sbuf[tid >> 6] = sm;
  __syncthreads();
  sm = sbuf[0] + sbuf[1];
  S[(size_t)row * 128 + tid] = e / sm;
}

#define FMA4(acc, s, v)                  \
  acc.x = fmaf(s, v.x, acc.x);           \
  acc.y = fmaf(s, v.y, acc.y);           \
  acc.z = fmaf(s, v.z, acc.z);           \
  acc.w = fmaf(s, v.w, acc.w)

// agg[b,m,d] = max(x1[b,m,d], qtc, qtb, qts, qtd, qtm); grid (BM), 256 threads x 4 d each
__global__ __launch_bounds__(256) void agg_max(const float* __restrict__ x0,
                                               const float* __restrict__ x1,
                                               const float* __restrict__ Sc,
                                               const float* __restrict__ Sb,
                                               const float* __restrict__ Sd1,
                                               const float* __restrict__ Sd2,
                                               const float* __restrict__ Sm,
                                               float* __restrict__ agg) {
  const int bm = blockIdx.x;
  const int b = bm >> 7;
  const int tid = threadIdx.x;
  __shared__ float w[5][128];
  if (tid < 128) {
    w[0][tid] = Sc[(size_t)bm * Nc + tid];
    w[1][tid] = Sb[(size_t)bm * Nc + tid];
    w[2][tid] = Sd1[(size_t)bm * Nc + tid];
    w[3][tid] = Sd2[(size_t)bm * Nc + tid];
    w[4][tid] = Sm[(size_t)bm * Nc + tid];
  }
  __syncthreads();
  const int d0 = tid * 4;
  float4 qc = {0, 0, 0, 0}, qb = {0, 0, 0, 0}, qs = {0, 0, 0, 0};
  float4 qd = {0, 0, 0, 0}, qm = {0, 0, 0, 0};
  const float* X0b = x0 + (size_t)b * Nc * Dc;
  const float* X1b = x1 + (size_t)b * Nc * Dc;
  for (int n = 0; n < Nc; n++) {
    float4 xv = *reinterpret_cast<const float4*>(&X0b[(size_t)n * Dc + d0]);
    float4 yv = *reinterpret_cast<const float4*>(&X1b[(size_t)n * Dc + d0]);
    float wc = w[0][n], wb = w[1][n], ws = w[2][n], wd = w[3][n], wm = w[4][n];
    FMA4(qc, wc, xv);
    FMA4(qb, wb, xv);
    FMA4(qs, ws, xv);
    FMA4(qd, wd, yv);
    FMA4(qm, wm, xv);
  }
  float4 x1v = *reinterpret_cast<const float4*>(&x1[(size_t)bm * Dc + d0]);
  float4 r;
  r.x = fmaxf(x1v.x, fmaxf(fmaxf(qs.x, qc.x), fmaxf(fmaxf(qd.x, qb.x), qm.x)));
  r.y = fmaxf(x1v.y, fmaxf(fmaxf(qs.y, qc.y), fmaxf(fmaxf(qd.y, qb.y), qm.y)));
  r.z = fmaxf(x1v.z, fmaxf(fmaxf(qs.z, qc.z), fmaxf(fmaxf(qd.z, qb.z), qm.z)));
  r.w = fmaxf(x1v.w, fmaxf(fmaxf(qs.w, qc.w), fmaxf(fmaxf(qd.w, qb.w), qm.w)));
  *reinterpret_cast<float4*>(&agg[(size_t)bm * Dc + d0]) = r;
}

// u[d2] = sum_h Wp1[d2,h]*vp[h]; grid (2*Dc), 64 threads
__global__ __launch_bounds__(64) void compute_u(const float* __restrict__ Wp1,
                                                const float* __restrict__ vp,
                                                float* __restrict__ u) {
  const int d2 = blockIdx.x;
  const int tid = threadIdx.x;
  float p = 0.f;
  #pragma unroll
  for (int h = tid; h < Hc; h += 64) p = fmaf(Wp1[(size_t)d2 * Hc + h], vp[h], p);
  #pragma unroll
  for (int o = 32; o; o >>= 1) p += __shfl_down(p, o, 64);
  if (tid == 0) u[d2] = p;
}

// score[bm] = x1[bm,:].u[0:D] + agg[bm,:].u[D:2D]   (rq@Wp2 term is softmax-invariant)
__global__ __launch_bounds__(256) void final_scores(const float* __restrict__ x1,
                                                    const float* __restrict__ agg,
                                                    const float* __restrict__ u,
                                                    float* __restrict__ score) {
  const int bm = blockIdx.x;
  const int tid = threadIdx.x;
  float p = 0.f;
  #pragma unroll
  for (int d = tid; d < Dc; d += 256)
    p = fmaf(x1[(size_t)bm * Dc + d], u[d], fmaf(agg[(size_t)bm * Dc + d], u[Dc + d], p));
  __shared__ float buf4[4];
  p = block_sum256(p, buf4);
  if (tid == 0) score[bm] = p;
}

// softmax over raw scores (inline) + out[b,j] = relu(sum_m sp[m]*cat[b,m,:].Wpred[:,j]+bpred)
__global__ __launch_bounds__(256) void final_out(const float* __restrict__ x1,
                                                 const float* __restrict__ agg,
                                                 const float* __restrict__ score,
                                                 const float* __restrict__ Wpred,
                                                 const float* __restrict__ bpred,
                                                 float* __restrict__ out) {
  const int b = blockIdx.x;
  const int tid = threadIdx.x;
  __shared__ float spL[128];
  __shared__ float mbuf[2], sbuf[2];
  if (tid < 128) {
    float x = score[b * Nc + tid];
    float mx = x;
    #pragma unroll
    for (int o = 32; o; o >>= 1) mx = fmaxf(mx, __shfl_down(mx, o, 64));
    if ((tid & 63) == 0) mbuf[tid >> 6] = mx;
  }
  __syncthreads();
  if (tid < 128) {
    float x = score[b * Nc + tid];
    float mx = fmaxf(mbuf[0], mbuf[1]);
    float e = __expf(x - mx);
    float sm = e;
    #pragma unroll
    for (int o = 32; o; o >>= 1) sm += __shfl_down(sm, o, 64);
    if ((tid & 63) == 0) sbuf[tid >> 6] = sm;
    spL[tid] = e;
  }
  __syncthreads();
  const float inv = 1.f / (sbuf[0] + sbuf[1]);
  const int d2 = tid * 8;
  float w0[8], w1[8];
  #pragma unroll
  for (int i = 0; i < 8; i++) {
    w0[i] = Wpred[(size_t)(d2 + i) * 2 + 0];
    w1[i] = Wpred[(size_t)(d2 + i) * 2 + 1];
  }
  const float* src = (d2 < Dc) ? (x1 + (size_t)b * Nc * Dc + d2)
                               : (agg + (size_t)b * Nc * Dc + (d2 - Dc));
  float p0 = 0.f, p1 = 0.f;
  for (int m = 0; m < Nc; m++) {
    float s = spL[m] * inv;
    const float* r = src + (size_t)m * Dc;
    #pragma unroll
    for (int i = 0; i < 8; i++) {
      float sc = s * r[i];
      p0 = fmaf(sc, w0[i], p0);
      p1 = fmaf(sc, w1[i], p1);
    }
  }
  #pragma unroll
  for (int o = 32; o; o >>= 1) {
    p0 += __shfl_down(p0, o, 64);
    p1 += __shfl_down(p1, o, 64);
  }
  __shared__ float r0[4], r1[4];
  const int w = tid >> 6, lane = tid & 63;
  if (lane == 0) { r0[w] = p0; r1[w] = p1; }
  __syncthreads();
  if (tid == 0) {
    float q0 = r0[0] + r0[1] + r0[2] + r0[3] + bpred[0];
    float q1 = r1[0] + r1[1] + r1[2] + r1[3] + bpred[1];
    out[b * 2 + 0] = fmaxf(q0, 0.f);
    out[b * 2 + 1] = fmaxf(q1, 0.f);
  }
}

extern "C" void kernel_launch(void* const* d_in, const int* in_sizes, int n_in,
                              void* d_out, int out_size, void* d_ws, size_t ws_size,
                              hipStream_t stream) {
  const float* x0    = (const float*)d_in[0];
  const float* x1    = (const float*)d_in[1];
  const float* Wc1   = (const float*)d_in[2];
  const float* Wc2   = (const float*)d_in[3];
  const float* vc    = (const float*)d_in[4];
  const float* Wb    = (const float*)d_in[5];
  const float* Wd1   = (const float*)d_in[6];
  const float* vd1   = (const float*)d_in[7];
  const float* Wd2   = (const float*)d_in[8];
  const float* vd2   = (const float*)d_in[9];
  const float* Wm    = (const float*)d_in[10];
  const float* vm    = (const float*)d_in[11];
  // d_in[12]=Wq, d_in[13]=vq, d_in[15]=Wp2: provably dead (softmax shift-invariance)
  const float* Wp1   = (const float*)d_in[14];
  const float* vp    = (const float*)d_in[16];
  const float* Wpred = (const float*)d_in[17];
  const float* bpred = (const float*)d_in[18];
  float* out = (float*)d_out;

  float* ws = (float*)d_ws;
  float* C1     = ws;               // [BM, 2H] fp32 (x0@[Wc1|Wm]); aliased as agg later
  float* C2     = C1 + 1048576;     // [BM, 2H] fp32 (x1@[Wc2|Wm])
  float* sc     = C2 + 1048576;     // 5 contiguous score tensors [B,M,N] = 131072 each
  float* sb     = sc + 131072;
  float* sd1    = sb + 131072;
  float* sd2    = sd1 + 131072;
  float* smv    = sd2 + 131072;
  float* u      = smv + 131072;     // [2D]
  float* score2 = u + 2048;         // [B*M]
  ushort* x0h   = (ushort*)(score2 + 1024);   // [BM, D] fp16
  ushort* x1h   = x0h + 1048576;
  ushort* W1T   = x1h + 1048576;    // [2H=1024, D] fp16: rows 0-511 Wc1^T, 512-1023 Wm^T
  ushort* W2T   = W1T + 1048576;    // rows 0-511 Wc2^T, 512-1023 Wm^T
  ushort* WbT   = W2T + 1048576;    // [D, D] fp16 (Wb^T)
  ushort* xWbh  = WbT + 1048576;    // [BM, D] fp16 (x0@Wb)
  ushort* wdT1  = xWbh + 1048576;   // [H, D] fp16
  ushort* wdT2  = wdT1 + 524288;
  float* agg    = C1;               // alias: C1 dead after addtanh; agg written after
  // total ~25.7 MB

  // --- input/weight conversion (2 launches) ---
  cvt_both<<<1024, 256, 0, stream>>>(x0, x1, x0h, x1h);
  TJobs tj;
  tj.src[0] = Wd1; tj.dst[0] = wdT1;            tj.J[0] = Hc;
  tj.src[1] = Wd2; tj.dst[1] = wdT2;            tj.J[1] = Hc;
  tj.src[2] = Wc1; tj.dst[2] = W1T;             tj.J[2] = Hc;
  tj.src[3] = Wm;  tj.dst[3] = W1T + 512 * Dc;  tj.J[3] = Hc;
  tj.src[4] = Wc2; tj.dst[4] = W2T;             tj.J[4] = Hc;
  tj.src[5] = Wm;  tj.dst[5] = W2T + 512 * Dc;  tj.J[5] = Hc;
  tj.src[6] = Wb;  tj.dst[6] = WbT;             tj.J[6] = Dc;
  conv_transpose_multi<<<dim3(16, 16, 7), 256, 0, stream>>>(tj);

  // --- projections (fp16 MFMA) ---
  gemm_bt<<<dim3(16, 16, 1), 256, 0, stream>>>(x0h, W1T, C1, nullptr, Dc, 1024, 0, 0, 0);
  gemm_bt<<<dim3(16, 16, 1), 256, 0, stream>>>(x1h, W2T, C2, nullptr, Dc, 1024, 0, 0, 0);
  gemm_bt<<<dim3(16, 16, 1), 256, 0, stream>>>(x0h, WbT, nullptr, xWbh, Dc, 1024, 0, 0, 0);
  // bilinear scores: sb[b,m,n] = x1[b,m,:].xWb[b,n,:]
  gemm_bt<<<dim3(2, 2, 8), 256, 0, stream>>>(x1h, xWbh, sb, nullptr, Dc, 128,
                                             131072, 131072, 16384);

  // --- concat + minus scores (one dispatch) ---
  addtanh_tiled2<<<dim3(8, 8, 16), 256, 0, stream>>>(C1, C2, vc, vm, sc, smv);

  // --- dot scores (fp16 MFMA, pk_mul staging, both directions) ---
  (void)hipMemsetAsync(sd1, 0, 2 * 131072 * sizeof(float), stream);
  dot_scores_mfma4<<<dim3(2, BM, 2), 256, 0, stream>>>(x0h, x1h, wdT1, wdT2, vd1, vd2, sd1);

  // --- softmax over n for all 5 score tensors (contiguous rows) ---
  softmax128<<<5 * BM, 128, 0, stream>>>(sc);

  // --- weighted sums + elementwise max (agg aliases C1) ---
  agg_max<<<BM, 256, 0, stream>>>(x0, x1, sc, sb, sd1, sd2, smv, agg);

  // --- aggregation (rq path dropped; Wp1@vp prefolded; softmax fused into final_out) ---
  compute_u<<<2 * Dc, 64, 0, stream>>>(Wp1, vp, u);
  final_scores<<<BM, 256, 0, stream>>>(x1, agg, u, score2);
  final_out<<<Bc, 256, 0, stream>>>(x1, agg, score2, Wpred, bpred, out);
}